// Round 1
// baseline (3351.336 us; speedup 1.0000x reference)
//
#include <hip/hip_runtime.h>

#define T_ 8
#define N_ 50000
#define E_ 800000
#define C_ 64

// ---------------------------------------------------------------------------
// 1) degree scatter: deg[src[e]] += w[e]
__global__ void deg_kernel(const int* __restrict__ src, const float* __restrict__ w,
                           float* __restrict__ deg, int E) {
    int e = blockIdx.x * blockDim.x + threadIdx.x;
    if (e < E) atomicAdd(&deg[src[e]], w[e]);
}

// 2) dinv in place: deg -> (deg>0 ? rsqrt(max(deg,1e-12)) : 0)
__global__ void dinv_kernel(float* __restrict__ deg, int N) {
    int n = blockIdx.x * blockDim.x + threadIdx.x;
    if (n < N) {
        float d = deg[n];
        deg[n] = d > 0.f ? rsqrtf(fmaxf(d, 1e-12f)) : 0.f;
    }
}

// 3) nw[e] = -w[e] * dinv[src[e]] * dinv[dst[e]]
__global__ void nw_kernel(const int* __restrict__ src, const int* __restrict__ dst,
                          const float* __restrict__ w, const float* __restrict__ dinv,
                          float* __restrict__ nw, int E) {
    int e = blockIdx.x * blockDim.x + threadIdx.x;
    if (e < E) nw[e] = -w[e] * dinv[src[e]] * dinv[dst[e]];
}

// 4) TX1 scatter: one 64-lane wave per (t,e); lane = channel.
//    TX1[t, dst[e], lane] += nw[e] * x[t, src[e], lane]
__global__ void scatter_kernel(const int* __restrict__ src, const int* __restrict__ dst,
                               const float* __restrict__ nw, const float* __restrict__ x,
                               float* __restrict__ tx1) {
    long long gid = (long long)blockIdx.x * blockDim.x + threadIdx.x;
    int lane = (int)(gid & 63);
    long long grp = gid >> 6;              // [0, T*E): e fastest for load coalescing
    int e = (int)(grp % E_);
    int t = (int)(grp / E_);
    int s = src[e];
    int d = dst[e];
    float nwv = nw[e];
    float xv = x[((long long)t * N_ + s) * C_ + lane];
    atomicAdd(&tx1[((long long)t * N_ + d) * C_ + lane], nwv * xv);
}

// 5) fused per-node compute:
//    Z  = sigmoid(x@Wz0 + TX1@Wz1 + bz)     (bz = bxz + bhz)
//    Ht = tanh   (x@Wh0 + TX1@Wh1 + bh)     (bh = bxh + bhh)
//    out = relu((1-Z)*Ht) @ W_lin + b_lin
//    One wave per (t,n) row; lane = output channel; weights in 64 KiB LDS.
__global__ __launch_bounds__(256) void node_kernel(
        const float* __restrict__ x, const float* __restrict__ tx1,
        const float* __restrict__ Wz0, const float* __restrict__ Wz1,
        const float* __restrict__ bxz, const float* __restrict__ bhz,
        const float* __restrict__ Wh0, const float* __restrict__ Wh1,
        const float* __restrict__ bxh, const float* __restrict__ bhh,
        const float* __restrict__ Wlin, const float* __restrict__ blin,
        float* __restrict__ out, long long TN) {
    __shared__ float sWz0[64 * 64];
    __shared__ float sWz1[64 * 64];
    __shared__ float sWh0[64 * 64];
    __shared__ float sWh1[64 * 64];   // exactly 64 KiB total

    for (int i = threadIdx.x; i < 64 * 64; i += 256) {
        sWz0[i] = Wz0[i];
        sWz1[i] = Wz1[i];
        sWh0[i] = Wh0[i];
        sWh1[i] = Wh1[i];
    }
    int lane = threadIdx.x & 63;
    int wid  = threadIdx.x >> 6;   // 0..3
    // per-lane constants kept in registers (LDS is full)
    float bz_r  = bxz[lane] + bhz[lane];
    float bh_r  = bxh[lane] + bhh[lane];
    float wl_r  = Wlin[lane];
    float bl_r  = blin[0];
    __syncthreads();

    long long row = (long long)blockIdx.x * 4 + wid;
    if (row >= TN) return;

    const float* xr = x   + row * C_;
    const float* tr = tx1 + row * C_;
    float xv = xr[lane];
    float tv = tr[lane];
    float az = bz_r;
    float ah = bh_r;
#pragma unroll
    for (int k = 0; k < 64; ++k) {
        float xk = __shfl(xv, k);
        float tk = __shfl(tv, k);
        az += xk * sWz0[k * 64 + lane] + tk * sWz1[k * 64 + lane];
        ah += xk * sWh0[k * 64 + lane] + tk * sWh1[k * 64 + lane];
    }
    float z  = 1.f / (1.f + __expf(-az));
    float ht = tanhf(ah);
    float h  = fmaxf((1.f - z) * ht, 0.f);
    float p  = h * wl_r;
#pragma unroll
    for (int off = 32; off; off >>= 1) p += __shfl_down(p, off);
    if (lane == 0) out[row] = p + bl_r;
}

extern "C" void kernel_launch(void* const* d_in, const int* in_sizes, int n_in,
                              void* d_out, int out_size, void* d_ws, size_t ws_size,
                              hipStream_t stream) {
    const float* x    = (const float*)d_in[0];
    const int*   ei   = (const int*)d_in[1];     // (2,E): src then dst
    const float* w    = (const float*)d_in[2];
    const float* Wxz0 = (const float*)d_in[3];
    const float* Wxz1 = (const float*)d_in[4];
    const float* bxz  = (const float*)d_in[5];
    const float* bhz  = (const float*)d_in[8];
    const float* Wxh0 = (const float*)d_in[15];
    const float* Wxh1 = (const float*)d_in[16];
    const float* bxh  = (const float*)d_in[17];
    const float* bhh  = (const float*)d_in[20];
    const float* Wlin = (const float*)d_in[21];
    const float* blin = (const float*)d_in[22];
    float* out = (float*)d_out;

    const int* src = ei;
    const int* dst = ei + E_;

    // workspace layout
    char* ws = (char*)d_ws;
    float* deg = (float*)ws;                               // N floats (doubles as dinv)
    size_t off_nw  = ((size_t)N_ * 4 + 511) / 512 * 512;   // 200192
    float* nw  = (float*)(ws + off_nw);                    // E floats
    size_t off_tx = off_nw + ((size_t)E_ * 4 + 511) / 512 * 512;
    float* tx1 = (float*)(ws + off_tx);                    // T*N*64 floats = 102.4 MB

    // zero deg and tx1 (harness poisons ws each call)
    hipMemsetAsync(deg, 0, (size_t)N_ * 4, stream);
    hipMemsetAsync(tx1, 0, (size_t)T_ * N_ * C_ * 4, stream);

    deg_kernel<<<(E_ + 255) / 256, 256, 0, stream>>>(src, w, deg, E_);
    dinv_kernel<<<(N_ + 255) / 256, 256, 0, stream>>>(deg, N_);
    nw_kernel<<<(E_ + 255) / 256, 256, 0, stream>>>(src, dst, w, deg, nw, E_);

    // one wave per (t,e): total threads = T*E*64
    long long scat_threads = (long long)T_ * E_ * 64;
    int scat_blocks = (int)((scat_threads + 255) / 256);
    scatter_kernel<<<scat_blocks, 256, 0, stream>>>(src, dst, nw, x, tx1);

    long long TN = (long long)T_ * N_;
    int node_blocks = (int)((TN + 3) / 4);
    node_kernel<<<node_blocks, 256, 0, stream>>>(
        x, tx1, Wxz0, Wxz1, bxz, bhz, Wxh0, Wxh1, bxh, bhh, Wlin, blin, out, TN);
}

// Round 2
// 1662.860 us; speedup vs baseline: 2.0154x; 2.0154x over previous
//
#include <hip/hip_runtime.h>

#define T_ 8
#define N_ 50000
#define E_ 800000
#define C_ 64

typedef __attribute__((ext_vector_type(8))) short bf16x8;
typedef __attribute__((ext_vector_type(4))) float f32x4;

__device__ inline short f2bf(float f) {
    union { float f; unsigned int u; } v; v.f = f;
    unsigned int u = v.u + 0x7FFFu + ((v.u >> 16) & 1u);  // RNE
    return (short)(u >> 16);
}

// ---------------------------------------------------------------------------
// 1) degree scatter: deg[src[e]] += w[e]
__global__ void deg_kernel(const int* __restrict__ src, const float* __restrict__ w,
                           float* __restrict__ deg, int E) {
    int e = blockIdx.x * blockDim.x + threadIdx.x;
    if (e < E) atomicAdd(&deg[src[e]], w[e]);
}

// 2) dinv in place
__global__ void dinv_kernel(float* __restrict__ deg, int N) {
    int n = blockIdx.x * blockDim.x + threadIdx.x;
    if (n < N) {
        float d = deg[n];
        deg[n] = d > 0.f ? rsqrtf(fmaxf(d, 1e-12f)) : 0.f;
    }
}

// 3) nw[e] = -w[e] * dinv[src[e]] * dinv[dst[e]]
__global__ void nw_kernel(const int* __restrict__ src, const int* __restrict__ dst,
                          const float* __restrict__ w, const float* __restrict__ dinv,
                          float* __restrict__ nw, int E) {
    int e = blockIdx.x * blockDim.x + threadIdx.x;
    if (e < E) nw[e] = -w[e] * dinv[src[e]] * dinv[dst[e]];
}

// 4) TX1 scatter: one 64-lane wave per (t,e); lane = channel. t outermost so each
//    t-phase's tx1 slice (12.8 MB) is L2-resident.
__global__ void scatter_kernel(const int* __restrict__ src, const int* __restrict__ dst,
                               const float* __restrict__ nw, const float* __restrict__ x,
                               float* __restrict__ tx1) {
    long long gid = (long long)blockIdx.x * blockDim.x + threadIdx.x;
    int lane = (int)(gid & 63);
    long long grp = gid >> 6;
    int e = (int)(grp % E_);
    int t = (int)(grp / E_);
    int s = src[e];
    int d = dst[e];
    float nwv = nw[e];
    float xv = x[((long long)t * N_ + s) * C_ + lane];
    atomicAdd(&tx1[((long long)t * N_ + d) * C_ + lane], nwv * xv);
}

// 5) weight prep: bf16-convert + swizzle 4 matrices (Wxz0, Wxz1, Wxh0, Wxh1) into
//    MFMA B-fragment order: idx = mat*4096 + (c*2+kb)*512 + lane*8 + j
//    holds W[kb*32 + (lane>>4)*8 + j][c*16 + (lane&15)]
__global__ void wprep_kernel(const float* __restrict__ Wz0, const float* __restrict__ Wz1,
                             const float* __restrict__ Wh0, const float* __restrict__ Wh1,
                             short* __restrict__ swz) {
    int idx = blockIdx.x * blockDim.x + threadIdx.x;
    if (idx >= 4 * 4096) return;
    int j = idx & 7;
    int lane = (idx >> 3) & 63;
    int kb = (idx >> 9) & 1;
    int c = (idx >> 10) & 3;
    int mat = idx >> 12;
    const float* W = (mat == 0) ? Wz0 : (mat == 1) ? Wz1 : (mat == 2) ? Wh0 : Wh1;
    int k = kb * 32 + (lane >> 4) * 8 + j;
    int n = c * 16 + (lane & 15);
    swz[idx] = f2bf(W[k * 64 + n]);
}

// 6) MFMA node kernel: 4 waves/block, 16 rows/wave, 64 rows/block.
//    az = x@Wz0 + tx1@Wz1 + (bxz+bhz); ah = x@Wh0 + tx1@Wh1 + (bxh+bhh)
//    out = relu((1-sigmoid(az))*tanh(ah)) @ Wlin + blin
__global__ __launch_bounds__(256) void node_kernel(
        const float* __restrict__ x, const float* __restrict__ tx1,
        const short* __restrict__ swz,
        const float* __restrict__ bxz, const float* __restrict__ bhz,
        const float* __restrict__ bxh, const float* __restrict__ bhh,
        const float* __restrict__ Wlin, const float* __restrict__ blin,
        float* __restrict__ out) {
    __shared__ short lds[4 * 4096];  // 32 KB swizzled bf16 weights

    {
        const int4* s4 = (const int4*)swz;
        int4* l4 = (int4*)lds;
        for (int i = threadIdx.x; i < 2048; i += 256) l4[i] = s4[i];
    }
    __syncthreads();

    int lane = threadIdx.x & 63;
    int wid = threadIdx.x >> 6;
    int c16 = lane & 15;   // A-row / C-col index within tile
    int kq = lane >> 4;    // 0..3: A k-quad / C row-group
    long long row_base = (long long)blockIdx.x * 64 + wid * 16;

    // ---- A fragments: x and tx1 rows, fp32 -> bf16 in-register ----
    const float* xr = x + (row_base + c16) * C_ + kq * 8;
    const float* tr = tx1 + (row_base + c16) * C_ + kq * 8;
    bf16x8 ax0, ax1, at0, at1;
    {
        float4 a = *(const float4*)(xr);
        float4 b = *(const float4*)(xr + 4);
        float4 cc = *(const float4*)(xr + 32);
        float4 dd = *(const float4*)(xr + 36);
        ax0[0] = f2bf(a.x); ax0[1] = f2bf(a.y); ax0[2] = f2bf(a.z); ax0[3] = f2bf(a.w);
        ax0[4] = f2bf(b.x); ax0[5] = f2bf(b.y); ax0[6] = f2bf(b.z); ax0[7] = f2bf(b.w);
        ax1[0] = f2bf(cc.x); ax1[1] = f2bf(cc.y); ax1[2] = f2bf(cc.z); ax1[3] = f2bf(cc.w);
        ax1[4] = f2bf(dd.x); ax1[5] = f2bf(dd.y); ax1[6] = f2bf(dd.z); ax1[7] = f2bf(dd.w);
    }
    {
        float4 a = *(const float4*)(tr);
        float4 b = *(const float4*)(tr + 4);
        float4 cc = *(const float4*)(tr + 32);
        float4 dd = *(const float4*)(tr + 36);
        at0[0] = f2bf(a.x); at0[1] = f2bf(a.y); at0[2] = f2bf(a.z); at0[3] = f2bf(a.w);
        at0[4] = f2bf(b.x); at0[5] = f2bf(b.y); at0[6] = f2bf(b.z); at0[7] = f2bf(b.w);
        at1[0] = f2bf(cc.x); at1[1] = f2bf(cc.y); at1[2] = f2bf(cc.z); at1[3] = f2bf(cc.w);
        at1[4] = f2bf(dd.x); at1[5] = f2bf(dd.y); at1[6] = f2bf(dd.z); at1[7] = f2bf(dd.w);
    }

    // ---- accumulators, bias-initialized ----
    f32x4 az[4], ah[4];
#pragma unroll
    for (int c = 0; c < 4; ++c) {
        int col = c * 16 + c16;
        float bz = bxz[col] + bhz[col];
        float bh = bxh[col] + bhh[col];
        az[c] = (f32x4){bz, bz, bz, bz};
        ah[c] = (f32x4){bh, bh, bh, bh};
    }

    // ---- MFMA main: per col-tile, 8 B-frag ds_read_b128 + 8 mfma ----
#pragma unroll
    for (int c = 0; c < 4; ++c) {
        const short* base = lds + lane * 8;
        bf16x8 bz0k0 = *(const bf16x8*)(base + 0 * 4096 + (c * 2 + 0) * 512);
        bf16x8 bz0k1 = *(const bf16x8*)(base + 0 * 4096 + (c * 2 + 1) * 512);
        bf16x8 bz1k0 = *(const bf16x8*)(base + 1 * 4096 + (c * 2 + 0) * 512);
        bf16x8 bz1k1 = *(const bf16x8*)(base + 1 * 4096 + (c * 2 + 1) * 512);
        bf16x8 bh0k0 = *(const bf16x8*)(base + 2 * 4096 + (c * 2 + 0) * 512);
        bf16x8 bh0k1 = *(const bf16x8*)(base + 2 * 4096 + (c * 2 + 1) * 512);
        bf16x8 bh1k0 = *(const bf16x8*)(base + 3 * 4096 + (c * 2 + 0) * 512);
        bf16x8 bh1k1 = *(const bf16x8*)(base + 3 * 4096 + (c * 2 + 1) * 512);
        az[c] = __builtin_amdgcn_mfma_f32_16x16x32_bf16(ax0, bz0k0, az[c], 0, 0, 0);
        az[c] = __builtin_amdgcn_mfma_f32_16x16x32_bf16(ax1, bz0k1, az[c], 0, 0, 0);
        az[c] = __builtin_amdgcn_mfma_f32_16x16x32_bf16(at0, bz1k0, az[c], 0, 0, 0);
        az[c] = __builtin_amdgcn_mfma_f32_16x16x32_bf16(at1, bz1k1, az[c], 0, 0, 0);
        ah[c] = __builtin_amdgcn_mfma_f32_16x16x32_bf16(ax0, bh0k0, ah[c], 0, 0, 0);
        ah[c] = __builtin_amdgcn_mfma_f32_16x16x32_bf16(ax1, bh0k1, ah[c], 0, 0, 0);
        ah[c] = __builtin_amdgcn_mfma_f32_16x16x32_bf16(at0, bh1k0, ah[c], 0, 0, 0);
        ah[c] = __builtin_amdgcn_mfma_f32_16x16x32_bf16(at1, bh1k1, ah[c], 0, 0, 0);
    }

    // ---- epilogue: activations + Wlin dot, all fp32 ----
    float part[4] = {0.f, 0.f, 0.f, 0.f};
#pragma unroll
    for (int c = 0; c < 4; ++c) {
        int col = c * 16 + c16;
        float wl = Wlin[col];
#pragma unroll
        for (int r = 0; r < 4; ++r) {
            float a = az[c][r];
            float b = ah[c][r];
            float z = 1.f / (1.f + __expf(-a));
            float aa = fabsf(b);
            float e = __expf(-2.f * aa);
            float ht = copysignf((1.f - e) / (1.f + e), b);
            float h = fmaxf((1.f - z) * ht, 0.f);
            part[r] += h * wl;
        }
    }
    // reduce across the 16 lanes sharing kq (xor over low 4 lane bits)
#pragma unroll
    for (int m = 1; m <= 8; m <<= 1) {
#pragma unroll
        for (int r = 0; r < 4; ++r) part[r] += __shfl_xor(part[r], m);
    }
    if (c16 == 0) {
        float bl = blin[0];
        long long row = row_base + kq * 4;
#pragma unroll
        for (int r = 0; r < 4; ++r) out[row + r] = part[r] + bl;
    }
}

extern "C" void kernel_launch(void* const* d_in, const int* in_sizes, int n_in,
                              void* d_out, int out_size, void* d_ws, size_t ws_size,
                              hipStream_t stream) {
    const float* x    = (const float*)d_in[0];
    const int*   ei   = (const int*)d_in[1];
    const float* w    = (const float*)d_in[2];
    const float* Wxz0 = (const float*)d_in[3];
    const float* Wxz1 = (const float*)d_in[4];
    const float* bxz  = (const float*)d_in[5];
    const float* bhz  = (const float*)d_in[8];
    const float* Wxh0 = (const float*)d_in[15];
    const float* Wxh1 = (const float*)d_in[16];
    const float* bxh  = (const float*)d_in[17];
    const float* bhh  = (const float*)d_in[20];
    const float* Wlin = (const float*)d_in[21];
    const float* blin = (const float*)d_in[22];
    float* out = (float*)d_out;

    const int* src = ei;
    const int* dst = ei + E_;

    // workspace layout: swz(32KB) | deg(N) | nw(E) | tx1(T*N*64)
    char* ws = (char*)d_ws;
    short* swz = (short*)ws;
    size_t off_deg = 32768;
    float* deg = (float*)(ws + off_deg);
    size_t off_nw = off_deg + ((size_t)N_ * 4 + 511) / 512 * 512;
    float* nw = (float*)(ws + off_nw);
    size_t off_tx = off_nw + ((size_t)E_ * 4 + 511) / 512 * 512;
    float* tx1 = (float*)(ws + off_tx);

    hipMemsetAsync(deg, 0, (size_t)N_ * 4, stream);
    hipMemsetAsync(tx1, 0, (size_t)T_ * N_ * C_ * 4, stream);

    deg_kernel<<<(E_ + 255) / 256, 256, 0, stream>>>(src, w, deg, E_);
    dinv_kernel<<<(N_ + 255) / 256, 256, 0, stream>>>(deg, N_);
    nw_kernel<<<(E_ + 255) / 256, 256, 0, stream>>>(src, dst, w, deg, nw, E_);
    wprep_kernel<<<(4 * 4096 + 255) / 256, 256, 0, stream>>>(Wxz0, Wxz1, Wxh0, Wxh1, swz);

    long long scat_threads = (long long)T_ * E_ * 64;
    int scat_blocks = (int)((scat_threads + 255) / 256);
    scatter_kernel<<<scat_blocks, 256, 0, stream>>>(src, dst, nw, x, tx1);

    long long TN = (long long)T_ * N_;
    int node_blocks = (int)(TN / 64);  // 400000 % 64 == 0
    node_kernel<<<node_blocks, 256, 0, stream>>>(
        x, tx1, swz, bxz, bhz, bxh, bhh, Wlin, blin, out);
}

// Round 3
// 655.893 us; speedup vs baseline: 5.1096x; 2.5353x over previous
//
#include <hip/hip_runtime.h>

#define T_ 8
#define N_ 50000
#define E_ 800000
#define C_ 64

typedef __attribute__((ext_vector_type(8))) short bf16x8;
typedef __attribute__((ext_vector_type(4))) float f32x4;

__device__ inline short f2bf(float f) {
    union { float f; unsigned int u; } v; v.f = f;
    unsigned int u = v.u + 0x7FFFu + ((v.u >> 16) & 1u);  // RNE
    return (short)(u >> 16);
}

// ---------------------------------------------------------------------------
// 1) histogram: degw[src]+=w (weighted, for dinv), cnt[dst]+=1 (for CSR)
__global__ void hist_kernel(const int* __restrict__ src, const int* __restrict__ dst,
                            const float* __restrict__ w,
                            float* __restrict__ degw, int* __restrict__ cnt, int E) {
    int e = blockIdx.x * blockDim.x + threadIdx.x;
    if (e < E) {
        atomicAdd(&degw[src[e]], w[e]);
        atomicAdd(&cnt[dst[e]], 1);
    }
}

// 2) dinv in place
__global__ void dinv_kernel(float* __restrict__ deg, int N) {
    int n = blockIdx.x * blockDim.x + threadIdx.x;
    if (n < N) {
        float d = deg[n];
        deg[n] = d > 0.f ? rsqrtf(fmaxf(d, 1e-12f)) : 0.f;
    }
}

// 3) exclusive scan of cnt -> rowptr (one workgroup, 1024 threads)
__global__ __launch_bounds__(1024) void scan_kernel(const int* __restrict__ cnt,
                                                    int* __restrict__ rowptr) {
    __shared__ int sums[1024];
    const int CH = (N_ + 1023) / 1024;  // 49
    int tid = threadIdx.x;
    int begin = tid * CH;
    int end = begin + CH < N_ ? begin + CH : N_;
    int s = 0;
    for (int i = begin; i < end; ++i) s += cnt[i];
    sums[tid] = s;
    __syncthreads();
    for (int off = 1; off < 1024; off <<= 1) {
        int v = (tid >= off) ? sums[tid - off] : 0;
        __syncthreads();
        sums[tid] += v;
        __syncthreads();
    }
    int run = (tid == 0) ? 0 : sums[tid - 1];
    for (int i = begin; i < end; ++i) {
        rowptr[i] = run;
        run += cnt[i];
    }
    if (tid == 1023) rowptr[N_] = run;
}

// 4) reorder edges into CSR-by-dst. Mutates rowptr: afterwards rowptr[d] == end(d),
//    start(d) == (d ? rowptr[d-1] : 0). Packs {src, nw} as int2.
__global__ void reorder_kernel(const int* __restrict__ src, const int* __restrict__ dst,
                               const float* __restrict__ w, const float* __restrict__ dinv,
                               int* __restrict__ rowptr, int2* __restrict__ es, int E) {
    int e = blockIdx.x * blockDim.x + threadIdx.x;
    if (e < E) {
        int s = src[e], d = dst[e];
        float nwv = -w[e] * dinv[s] * dinv[d];
        int pos = atomicAdd(&rowptr[d], 1);
        es[pos] = make_int2(s, __float_as_int(nwv));
    }
}

// 5) atomic-free gather: one wave per dst node, lane = channel, all T timesteps.
//    tx1[t,d,:] = sum_e nw[e] * x[t,src[e],:]
__global__ __launch_bounds__(256) void gather_kernel(const int* __restrict__ rowptr,
        const int2* __restrict__ es, const float* __restrict__ x,
        float* __restrict__ tx1) {
    int wave = blockIdx.x * 4 + (threadIdx.x >> 6);
    int lane = threadIdx.x & 63;
    if (wave >= N_) return;
    int d = wave;
    int start = d ? rowptr[d - 1] : 0;
    int end = rowptr[d];
    float acc[T_] = {0.f, 0.f, 0.f, 0.f, 0.f, 0.f, 0.f, 0.f};
    for (int base = start; base < end; base += 64) {
        int rem = end - base;
        int m = rem < 64 ? rem : 64;
        int2 pk = (lane < m) ? es[base + lane] : make_int2(0, 0);
        for (int k = 0; k < m; ++k) {
            int s = __shfl(pk.x, k);
            float nwv = __int_as_float(__shfl(pk.y, k));
            const float* xp = x + (long long)s * C_ + lane;
#pragma unroll
            for (int t = 0; t < T_; ++t)
                acc[t] += nwv * xp[(long long)t * N_ * C_];
        }
    }
#pragma unroll
    for (int t = 0; t < T_; ++t)
        tx1[((long long)t * N_ + d) * C_ + lane] = acc[t];
}

// 6) weight prep: bf16-convert + swizzle into MFMA B-fragment order
__global__ void wprep_kernel(const float* __restrict__ Wz0, const float* __restrict__ Wz1,
                             const float* __restrict__ Wh0, const float* __restrict__ Wh1,
                             short* __restrict__ swz) {
    int idx = blockIdx.x * blockDim.x + threadIdx.x;
    if (idx >= 4 * 4096) return;
    int j = idx & 7;
    int lane = (idx >> 3) & 63;
    int kb = (idx >> 9) & 1;
    int c = (idx >> 10) & 3;
    int mat = idx >> 12;
    const float* W = (mat == 0) ? Wz0 : (mat == 1) ? Wz1 : (mat == 2) ? Wh0 : Wh1;
    int k = kb * 32 + (lane >> 4) * 8 + j;
    int n = c * 16 + (lane & 15);
    swz[idx] = f2bf(W[k * 64 + n]);
}

// 7) MFMA node kernel: 4 waves/block, 16 rows/wave, 64 rows/block.
__global__ __launch_bounds__(256) void node_kernel(
        const float* __restrict__ x, const float* __restrict__ tx1,
        const short* __restrict__ swz,
        const float* __restrict__ bxz, const float* __restrict__ bhz,
        const float* __restrict__ bxh, const float* __restrict__ bhh,
        const float* __restrict__ Wlin, const float* __restrict__ blin,
        float* __restrict__ out) {
    __shared__ short lds[4 * 4096];  // 32 KB swizzled bf16 weights

    {
        const int4* s4 = (const int4*)swz;
        int4* l4 = (int4*)lds;
        for (int i = threadIdx.x; i < 2048; i += 256) l4[i] = s4[i];
    }
    __syncthreads();

    int lane = threadIdx.x & 63;
    int wid = threadIdx.x >> 6;
    int c16 = lane & 15;
    int kq = lane >> 4;
    long long row_base = (long long)blockIdx.x * 64 + wid * 16;

    const float* xr = x + (row_base + c16) * C_ + kq * 8;
    const float* tr = tx1 + (row_base + c16) * C_ + kq * 8;
    bf16x8 ax0, ax1, at0, at1;
    {
        float4 a = *(const float4*)(xr);
        float4 b = *(const float4*)(xr + 4);
        float4 cc = *(const float4*)(xr + 32);
        float4 dd = *(const float4*)(xr + 36);
        ax0[0] = f2bf(a.x); ax0[1] = f2bf(a.y); ax0[2] = f2bf(a.z); ax0[3] = f2bf(a.w);
        ax0[4] = f2bf(b.x); ax0[5] = f2bf(b.y); ax0[6] = f2bf(b.z); ax0[7] = f2bf(b.w);
        ax1[0] = f2bf(cc.x); ax1[1] = f2bf(cc.y); ax1[2] = f2bf(cc.z); ax1[3] = f2bf(cc.w);
        ax1[4] = f2bf(dd.x); ax1[5] = f2bf(dd.y); ax1[6] = f2bf(dd.z); ax1[7] = f2bf(dd.w);
    }
    {
        float4 a = *(const float4*)(tr);
        float4 b = *(const float4*)(tr + 4);
        float4 cc = *(const float4*)(tr + 32);
        float4 dd = *(const float4*)(tr + 36);
        at0[0] = f2bf(a.x); at0[1] = f2bf(a.y); at0[2] = f2bf(a.z); at0[3] = f2bf(a.w);
        at0[4] = f2bf(b.x); at0[5] = f2bf(b.y); at0[6] = f2bf(b.z); at0[7] = f2bf(b.w);
        at1[0] = f2bf(cc.x); at1[1] = f2bf(cc.y); at1[2] = f2bf(cc.z); at1[3] = f2bf(cc.w);
        at1[4] = f2bf(dd.x); at1[5] = f2bf(dd.y); at1[6] = f2bf(dd.z); at1[7] = f2bf(dd.w);
    }

    f32x4 az[4], ah[4];
#pragma unroll
    for (int c = 0; c < 4; ++c) {
        int col = c * 16 + c16;
        float bz = bxz[col] + bhz[col];
        float bh = bxh[col] + bhh[col];
        az[c] = (f32x4){bz, bz, bz, bz};
        ah[c] = (f32x4){bh, bh, bh, bh};
    }

#pragma unroll
    for (int c = 0; c < 4; ++c) {
        const short* base = lds + lane * 8;
        bf16x8 bz0k0 = *(const bf16x8*)(base + 0 * 4096 + (c * 2 + 0) * 512);
        bf16x8 bz0k1 = *(const bf16x8*)(base + 0 * 4096 + (c * 2 + 1) * 512);
        bf16x8 bz1k0 = *(const bf16x8*)(base + 1 * 4096 + (c * 2 + 0) * 512);
        bf16x8 bz1k1 = *(const bf16x8*)(base + 1 * 4096 + (c * 2 + 1) * 512);
        bf16x8 bh0k0 = *(const bf16x8*)(base + 2 * 4096 + (c * 2 + 0) * 512);
        bf16x8 bh0k1 = *(const bf16x8*)(base + 2 * 4096 + (c * 2 + 1) * 512);
        bf16x8 bh1k0 = *(const bf16x8*)(base + 3 * 4096 + (c * 2 + 0) * 512);
        bf16x8 bh1k1 = *(const bf16x8*)(base + 3 * 4096 + (c * 2 + 1) * 512);
        az[c] = __builtin_amdgcn_mfma_f32_16x16x32_bf16(ax0, bz0k0, az[c], 0, 0, 0);
        az[c] = __builtin_amdgcn_mfma_f32_16x16x32_bf16(ax1, bz0k1, az[c], 0, 0, 0);
        az[c] = __builtin_amdgcn_mfma_f32_16x16x32_bf16(at0, bz1k0, az[c], 0, 0, 0);
        az[c] = __builtin_amdgcn_mfma_f32_16x16x32_bf16(at1, bz1k1, az[c], 0, 0, 0);
        ah[c] = __builtin_amdgcn_mfma_f32_16x16x32_bf16(ax0, bh0k0, ah[c], 0, 0, 0);
        ah[c] = __builtin_amdgcn_mfma_f32_16x16x32_bf16(ax1, bh0k1, ah[c], 0, 0, 0);
        ah[c] = __builtin_amdgcn_mfma_f32_16x16x32_bf16(at0, bh1k0, ah[c], 0, 0, 0);
        ah[c] = __builtin_amdgcn_mfma_f32_16x16x32_bf16(at1, bh1k1, ah[c], 0, 0, 0);
    }

    float part[4] = {0.f, 0.f, 0.f, 0.f};
#pragma unroll
    for (int c = 0; c < 4; ++c) {
        int col = c * 16 + c16;
        float wl = Wlin[col];
#pragma unroll
        for (int r = 0; r < 4; ++r) {
            float a = az[c][r];
            float b = ah[c][r];
            float z = 1.f / (1.f + __expf(-a));
            float aa = fabsf(b);
            float e = __expf(-2.f * aa);
            float ht = copysignf((1.f - e) / (1.f + e), b);
            float h = fmaxf((1.f - z) * ht, 0.f);
            part[r] += h * wl;
        }
    }
#pragma unroll
    for (int m = 1; m <= 8; m <<= 1) {
#pragma unroll
        for (int r = 0; r < 4; ++r) part[r] += __shfl_xor(part[r], m);
    }
    if (c16 == 0) {
        float bl = blin[0];
        long long row = row_base + kq * 4;
#pragma unroll
        for (int r = 0; r < 4; ++r) out[row + r] = part[r] + bl;
    }
}

extern "C" void kernel_launch(void* const* d_in, const int* in_sizes, int n_in,
                              void* d_out, int out_size, void* d_ws, size_t ws_size,
                              hipStream_t stream) {
    const float* x    = (const float*)d_in[0];
    const int*   ei   = (const int*)d_in[1];
    const float* w    = (const float*)d_in[2];
    const float* Wxz0 = (const float*)d_in[3];
    const float* Wxz1 = (const float*)d_in[4];
    const float* bxz  = (const float*)d_in[5];
    const float* bhz  = (const float*)d_in[8];
    const float* Wxh0 = (const float*)d_in[15];
    const float* Wxh1 = (const float*)d_in[16];
    const float* bxh  = (const float*)d_in[17];
    const float* bhh  = (const float*)d_in[20];
    const float* Wlin = (const float*)d_in[21];
    const float* blin = (const float*)d_in[22];
    float* out = (float*)d_out;

    const int* src = ei;
    const int* dst = ei + E_;

    // workspace layout (512-aligned blocks):
    char* ws = (char*)d_ws;
    size_t off = 0;
    auto alloc = [&](size_t bytes) {
        char* p = ws + off;
        off = (off + bytes + 511) & ~(size_t)511;
        return p;
    };
    short* swz    = (short*)alloc(4 * 4096 * sizeof(short));   // 32 KB
    float* degw   = (float*)alloc((size_t)N_ * 4);             // -> dinv in place
    int*   cnt    = (int*)alloc((size_t)N_ * 4);
    int*   rowptr = (int*)alloc(((size_t)N_ + 1) * 4);
    int2*  es     = (int2*)alloc((size_t)E_ * 8);              // 6.4 MB
    float* tx1    = (float*)alloc((size_t)T_ * N_ * C_ * 4);   // 102.4 MB

    hipMemsetAsync(degw, 0, (size_t)N_ * 4, stream);
    hipMemsetAsync(cnt, 0, (size_t)N_ * 4, stream);

    hist_kernel<<<(E_ + 255) / 256, 256, 0, stream>>>(src, dst, w, degw, cnt, E_);
    dinv_kernel<<<(N_ + 255) / 256, 256, 0, stream>>>(degw, N_);
    scan_kernel<<<1, 1024, 0, stream>>>(cnt, rowptr);
    reorder_kernel<<<(E_ + 255) / 256, 256, 0, stream>>>(src, dst, w, degw, rowptr, es, E_);
    wprep_kernel<<<(4 * 4096 + 255) / 256, 256, 0, stream>>>(Wxz0, Wxz1, Wxh0, Wxh1, swz);

    int gather_blocks = (N_ + 3) / 4;
    gather_kernel<<<gather_blocks, 256, 0, stream>>>(rowptr, es, x, tx1);

    long long TN = (long long)T_ * N_;
    int node_blocks = (int)(TN / 64);  // 400000 % 64 == 0
    node_kernel<<<node_blocks, 256, 0, stream>>>(
        x, tx1, swz, bxz, bhz, bxh, bhh, Wlin, blin, out);
}

// Round 4
// 558.122 us; speedup vs baseline: 6.0047x; 1.1752x over previous
//
#include <hip/hip_runtime.h>

#define T_ 8
#define N_ 50000
#define E_ 800000
#define C_ 64

typedef __attribute__((ext_vector_type(8))) short bf16x8;
typedef __attribute__((ext_vector_type(4))) float f32x4;

__device__ inline short f2bf(float f) {
    union { float f; unsigned int u; } v; v.f = f;
    unsigned int u = v.u + 0x7FFFu + ((v.u >> 16) & 1u);  // RNE
    return (short)(u >> 16);
}
__device__ inline float bf2f(unsigned short u) {
    union { unsigned int u; float f; } v; v.u = (unsigned int)u << 16;
    return v.f;
}

// ---------------------------------------------------------------------------
// 1) histogram: degw[src]+=w (for dinv), cnt[dst]+=1 (for CSR)
__global__ void hist_kernel(const int* __restrict__ src, const int* __restrict__ dst,
                            const float* __restrict__ w,
                            float* __restrict__ degw, int* __restrict__ cnt, int E) {
    int e = blockIdx.x * blockDim.x + threadIdx.x;
    if (e < E) {
        atomicAdd(&degw[src[e]], w[e]);
        atomicAdd(&cnt[dst[e]], 1);
    }
}

// 2) dinv in place
__global__ void dinv_kernel(float* __restrict__ deg, int N) {
    int n = blockIdx.x * blockDim.x + threadIdx.x;
    if (n < N) {
        float d = deg[n];
        deg[n] = d > 0.f ? rsqrtf(fmaxf(d, 1e-12f)) : 0.f;
    }
}

// 3) exclusive scan of cnt -> rowptr (one workgroup, 1024 threads)
__global__ __launch_bounds__(1024) void scan_kernel(const int* __restrict__ cnt,
                                                    int* __restrict__ rowptr) {
    __shared__ int sums[1024];
    const int CH = (N_ + 1023) / 1024;  // 49
    int tid = threadIdx.x;
    int begin = tid * CH;
    int end = begin + CH < N_ ? begin + CH : N_;
    int s = 0;
    for (int i = begin; i < end; ++i) s += cnt[i];
    sums[tid] = s;
    __syncthreads();
    for (int off = 1; off < 1024; off <<= 1) {
        int v = (tid >= off) ? sums[tid - off] : 0;
        __syncthreads();
        sums[tid] += v;
        __syncthreads();
    }
    int run = (tid == 0) ? 0 : sums[tid - 1];
    for (int i = begin; i < end; ++i) {
        rowptr[i] = run;
        run += cnt[i];
    }
    if (tid == 1023) rowptr[N_] = run;
}

// 4) reorder edges into CSR-by-dst. Afterwards rowptr[d] == end(d),
//    start(d) == (d ? rowptr[d-1] : 0). Packs {src, nw} as int2.
__global__ void reorder_kernel(const int* __restrict__ src, const int* __restrict__ dst,
                               const float* __restrict__ w, const float* __restrict__ dinv,
                               int* __restrict__ rowptr, int2* __restrict__ es, int E) {
    int e = blockIdx.x * blockDim.x + threadIdx.x;
    if (e < E) {
        int s = src[e], d = dst[e];
        float nwv = -w[e] * dinv[s] * dinv[d];
        int pos = atomicAdd(&rowptr[d], 1);
        es[pos] = make_int2(s, __float_as_int(nwv));
    }
}

// 5) x fp32 -> bf16 (same [t][n][c] layout). 8 elements/thread.
__global__ __launch_bounds__(256) void xcvt_kernel(const float* __restrict__ x,
                                                   unsigned short* __restrict__ xb) {
    long long i = ((long long)blockIdx.x * 256 + threadIdx.x) * 8;
    float4 a = *(const float4*)(x + i);
    float4 b = *(const float4*)(x + i + 4);
    bf16x8 o;
    o[0] = f2bf(a.x); o[1] = f2bf(a.y); o[2] = f2bf(a.z); o[3] = f2bf(a.w);
    o[4] = f2bf(b.x); o[5] = f2bf(b.y); o[6] = f2bf(b.z); o[7] = f2bf(b.w);
    *(bf16x8*)(xb + i) = o;
}

// 6) atomic-free gather, bf16 in/out, 4 channels/lane, 2 loads/edge.
//    lane = qt*16 + q: covers (t=qt, ch 4q..4q+3) and (t=qt+4, same ch).
//    tx1[t,d,:] = sum_e nw[e] * x[t,src[e],:]
__global__ __launch_bounds__(256) void gather_kernel(const int* __restrict__ rowptr,
        const int2* __restrict__ es, const unsigned short* __restrict__ xb,
        unsigned short* __restrict__ tx1b) {
    int d = blockIdx.x * 4 + (threadIdx.x >> 6);
    int lane = threadIdx.x & 63;
    if (d >= N_) return;
    int qt = lane >> 4;   // 0..3
    int q = lane & 15;    // 0..15
    int start = d ? rowptr[d - 1] : 0;
    int end = rowptr[d];
    float a0 = 0.f, a1 = 0.f, a2 = 0.f, a3 = 0.f;
    float b0 = 0.f, b1 = 0.f, b2 = 0.f, b3 = 0.f;
    const unsigned short* xbase = xb + ((long long)qt * N_) * C_ + q * 4;
    const long long toff = (long long)4 * N_ * C_;
    for (int base = start; base < end; base += 64) {
        int m = end - base;
        if (m > 64) m = 64;
        int2 pk = (lane < m) ? es[base + lane] : make_int2(0, 0);
        for (int k = 0; k < m; ++k) {
            int s = __shfl(pk.x, k);
            float nwv = __int_as_float(__shfl(pk.y, k));
            const unsigned short* xp = xbase + (long long)s * C_;
            ushort4 va = *(const ushort4*)xp;          // t = qt
            ushort4 vb = *(const ushort4*)(xp + toff); // t = qt+4
            a0 += nwv * bf2f(va.x); a1 += nwv * bf2f(va.y);
            a2 += nwv * bf2f(va.z); a3 += nwv * bf2f(va.w);
            b0 += nwv * bf2f(vb.x); b1 += nwv * bf2f(vb.y);
            b2 += nwv * bf2f(vb.z); b3 += nwv * bf2f(vb.w);
        }
    }
    ushort4 o0, o1;
    o0.x = (unsigned short)f2bf(a0); o0.y = (unsigned short)f2bf(a1);
    o0.z = (unsigned short)f2bf(a2); o0.w = (unsigned short)f2bf(a3);
    o1.x = (unsigned short)f2bf(b0); o1.y = (unsigned short)f2bf(b1);
    o1.z = (unsigned short)f2bf(b2); o1.w = (unsigned short)f2bf(b3);
    *(ushort4*)(tx1b + ((long long)qt * N_ + d) * C_ + q * 4) = o0;
    *(ushort4*)(tx1b + ((long long)(qt + 4) * N_ + d) * C_ + q * 4) = o1;
}

// 7) weight prep: bf16-convert + swizzle into MFMA B-fragment order
__global__ void wprep_kernel(const float* __restrict__ Wz0, const float* __restrict__ Wz1,
                             const float* __restrict__ Wh0, const float* __restrict__ Wh1,
                             short* __restrict__ swz) {
    int idx = blockIdx.x * blockDim.x + threadIdx.x;
    if (idx >= 4 * 4096) return;
    int j = idx & 7;
    int lane = (idx >> 3) & 63;
    int kb = (idx >> 9) & 1;
    int c = (idx >> 10) & 3;
    int mat = idx >> 12;
    const float* W = (mat == 0) ? Wz0 : (mat == 1) ? Wz1 : (mat == 2) ? Wh0 : Wh1;
    int k = kb * 32 + (lane >> 4) * 8 + j;
    int n = c * 16 + (lane & 15);
    swz[idx] = f2bf(W[k * 64 + n]);
}

// 8) MFMA node kernel: 4 waves/block, 16 rows/wave, 64 rows/block.
//    A-fragments loaded directly as bf16x8 from x_bf / tx1_bf.
__global__ __launch_bounds__(256) void node_kernel(
        const unsigned short* __restrict__ xb, const unsigned short* __restrict__ tx1b,
        const short* __restrict__ swz,
        const float* __restrict__ bxz, const float* __restrict__ bhz,
        const float* __restrict__ bxh, const float* __restrict__ bhh,
        const float* __restrict__ Wlin, const float* __restrict__ blin,
        float* __restrict__ out) {
    __shared__ short lds[4 * 4096];  // 32 KB swizzled bf16 weights

    {
        const int4* s4 = (const int4*)swz;
        int4* l4 = (int4*)lds;
        for (int i = threadIdx.x; i < 2048; i += 256) l4[i] = s4[i];
    }
    __syncthreads();

    int lane = threadIdx.x & 63;
    int wid = threadIdx.x >> 6;
    int c16 = lane & 15;
    int kq = lane >> 4;
    long long row_base = (long long)blockIdx.x * 64 + wid * 16;

    const unsigned short* xr = xb + (row_base + c16) * C_ + kq * 8;
    const unsigned short* tr = tx1b + (row_base + c16) * C_ + kq * 8;
    bf16x8 ax0 = *(const bf16x8*)(xr);
    bf16x8 ax1 = *(const bf16x8*)(xr + 32);
    bf16x8 at0 = *(const bf16x8*)(tr);
    bf16x8 at1 = *(const bf16x8*)(tr + 32);

    f32x4 az[4], ah[4];
#pragma unroll
    for (int c = 0; c < 4; ++c) {
        int col = c * 16 + c16;
        float bz = bxz[col] + bhz[col];
        float bh = bxh[col] + bhh[col];
        az[c] = (f32x4){bz, bz, bz, bz};
        ah[c] = (f32x4){bh, bh, bh, bh};
    }

#pragma unroll
    for (int c = 0; c < 4; ++c) {
        const short* base = lds + lane * 8;
        bf16x8 bz0k0 = *(const bf16x8*)(base + 0 * 4096 + (c * 2 + 0) * 512);
        bf16x8 bz0k1 = *(const bf16x8*)(base + 0 * 4096 + (c * 2 + 1) * 512);
        bf16x8 bz1k0 = *(const bf16x8*)(base + 1 * 4096 + (c * 2 + 0) * 512);
        bf16x8 bz1k1 = *(const bf16x8*)(base + 1 * 4096 + (c * 2 + 1) * 512);
        bf16x8 bh0k0 = *(const bf16x8*)(base + 2 * 4096 + (c * 2 + 0) * 512);
        bf16x8 bh0k1 = *(const bf16x8*)(base + 2 * 4096 + (c * 2 + 1) * 512);
        bf16x8 bh1k0 = *(const bf16x8*)(base + 3 * 4096 + (c * 2 + 0) * 512);
        bf16x8 bh1k1 = *(const bf16x8*)(base + 3 * 4096 + (c * 2 + 1) * 512);
        az[c] = __builtin_amdgcn_mfma_f32_16x16x32_bf16(ax0, bz0k0, az[c], 0, 0, 0);
        az[c] = __builtin_amdgcn_mfma_f32_16x16x32_bf16(ax1, bz0k1, az[c], 0, 0, 0);
        az[c] = __builtin_amdgcn_mfma_f32_16x16x32_bf16(at0, bz1k0, az[c], 0, 0, 0);
        az[c] = __builtin_amdgcn_mfma_f32_16x16x32_bf16(at1, bz1k1, az[c], 0, 0, 0);
        ah[c] = __builtin_amdgcn_mfma_f32_16x16x32_bf16(ax0, bh0k0, ah[c], 0, 0, 0);
        ah[c] = __builtin_amdgcn_mfma_f32_16x16x32_bf16(ax1, bh0k1, ah[c], 0, 0, 0);
        ah[c] = __builtin_amdgcn_mfma_f32_16x16x32_bf16(at0, bh1k0, ah[c], 0, 0, 0);
        ah[c] = __builtin_amdgcn_mfma_f32_16x16x32_bf16(at1, bh1k1, ah[c], 0, 0, 0);
    }

    float part[4] = {0.f, 0.f, 0.f, 0.f};
#pragma unroll
    for (int c = 0; c < 4; ++c) {
        int col = c * 16 + c16;
        float wl = Wlin[col];
#pragma unroll
        for (int r = 0; r < 4; ++r) {
            float a = az[c][r];
            float b = ah[c][r];
            float z = 1.f / (1.f + __expf(-a));
            float aa = fabsf(b);
            float e = __expf(-2.f * aa);
            float ht = copysignf((1.f - e) / (1.f + e), b);
            float h = fmaxf((1.f - z) * ht, 0.f);
            part[r] += h * wl;
        }
    }
#pragma unroll
    for (int m = 1; m <= 8; m <<= 1) {
#pragma unroll
        for (int r = 0; r < 4; ++r) part[r] += __shfl_xor(part[r], m);
    }
    if (c16 == 0) {
        float bl = blin[0];
        long long row = row_base + kq * 4;
#pragma unroll
        for (int r = 0; r < 4; ++r) out[row + r] = part[r] + bl;
    }
}

extern "C" void kernel_launch(void* const* d_in, const int* in_sizes, int n_in,
                              void* d_out, int out_size, void* d_ws, size_t ws_size,
                              hipStream_t stream) {
    const float* x    = (const float*)d_in[0];
    const int*   ei   = (const int*)d_in[1];
    const float* w    = (const float*)d_in[2];
    const float* Wxz0 = (const float*)d_in[3];
    const float* Wxz1 = (const float*)d_in[4];
    const float* bxz  = (const float*)d_in[5];
    const float* bhz  = (const float*)d_in[8];
    const float* Wxh0 = (const float*)d_in[15];
    const float* Wxh1 = (const float*)d_in[16];
    const float* bxh  = (const float*)d_in[17];
    const float* bhh  = (const float*)d_in[20];
    const float* Wlin = (const float*)d_in[21];
    const float* blin = (const float*)d_in[22];
    float* out = (float*)d_out;

    const int* src = ei;
    const int* dst = ei + E_;

    // workspace layout (512-aligned blocks):
    char* ws = (char*)d_ws;
    size_t off = 0;
    auto alloc = [&](size_t bytes) {
        char* p = ws + off;
        off = (off + bytes + 511) & ~(size_t)511;
        return p;
    };
    short* swz             = (short*)alloc(4 * 4096 * sizeof(short));        // 32 KB
    float* degw            = (float*)alloc((size_t)N_ * 4);                  // -> dinv
    int*   cnt             = (int*)alloc((size_t)N_ * 4);
    int*   rowptr          = (int*)alloc(((size_t)N_ + 1) * 4);
    int2*  es              = (int2*)alloc((size_t)E_ * 8);                   // 6.4 MB
    unsigned short* xb     = (unsigned short*)alloc((size_t)T_ * N_ * C_ * 2);  // 51.2 MB
    unsigned short* tx1b   = (unsigned short*)alloc((size_t)T_ * N_ * C_ * 2);  // 51.2 MB

    hipMemsetAsync(degw, 0, (size_t)N_ * 4, stream);
    hipMemsetAsync(cnt, 0, (size_t)N_ * 4, stream);

    hist_kernel<<<(E_ + 255) / 256, 256, 0, stream>>>(src, dst, w, degw, cnt, E_);
    dinv_kernel<<<(N_ + 255) / 256, 256, 0, stream>>>(degw, N_);
    scan_kernel<<<1, 1024, 0, stream>>>(cnt, rowptr);
    reorder_kernel<<<(E_ + 255) / 256, 256, 0, stream>>>(src, dst, w, degw, rowptr, es, E_);
    wprep_kernel<<<(4 * 4096 + 255) / 256, 256, 0, stream>>>(Wxz0, Wxz1, Wxh0, Wxh1, swz);

    // 25.6M elements / 8 per thread / 256 per block = 12500 blocks (exact)
    xcvt_kernel<<<12500, 256, 0, stream>>>(x, xb);

    int gather_blocks = (N_ + 3) / 4;
    gather_kernel<<<gather_blocks, 256, 0, stream>>>(rowptr, es, xb, tx1b);

    long long TN = (long long)T_ * N_;
    int node_blocks = (int)(TN / 64);  // 400000 % 64 == 0
    node_kernel<<<node_blocks, 256, 0, stream>>>(
        xb, tx1b, swz, bxz, bhz, bxh, bhh, Wlin, blin, out);
}

// Round 5
// 551.080 us; speedup vs baseline: 6.0814x; 1.0128x over previous
//
#include <hip/hip_runtime.h>

#define T_ 8
#define N_ 50000
#define E_ 800000
#define C_ 64

typedef __attribute__((ext_vector_type(8))) short bf16x8;
typedef __attribute__((ext_vector_type(4))) float f32x4;

__device__ inline short f2bf(float f) {
    union { float f; unsigned int u; } v; v.f = f;
    unsigned int u = v.u + 0x7FFFu + ((v.u >> 16) & 1u);  // RNE
    return (short)(u >> 16);
}
__device__ inline float bf2f_lo(unsigned int u) {  // low bf16 of packed word
    union { unsigned int u; float f; } v; v.u = u << 16;
    return v.f;
}
__device__ inline float bf2f_hi(unsigned int u) {  // high bf16 of packed word
    union { unsigned int u; float f; } v; v.u = u & 0xffff0000u;
    return v.f;
}

// ---------------------------------------------------------------------------
// 1) histogram: degw[src]+=w (for dinv), cnt[dst]+=1 (for CSR)
__global__ void hist_kernel(const int* __restrict__ src, const int* __restrict__ dst,
                            const float* __restrict__ w,
                            float* __restrict__ degw, int* __restrict__ cnt, int E) {
    int e = blockIdx.x * blockDim.x + threadIdx.x;
    if (e < E) {
        atomicAdd(&degw[src[e]], w[e]);
        atomicAdd(&cnt[dst[e]], 1);
    }
}

// 2) exclusive scan of cnt -> rowptr (one workgroup, 1024 threads)
__global__ __launch_bounds__(1024) void scan_kernel(const int* __restrict__ cnt,
                                                    int* __restrict__ rowptr) {
    __shared__ int sums[1024];
    const int CH = (N_ + 1023) / 1024;  // 49
    int tid = threadIdx.x;
    int begin = tid * CH;
    int end = begin + CH < N_ ? begin + CH : N_;
    int s = 0;
    for (int i = begin; i < end; ++i) s += cnt[i];
    sums[tid] = s;
    __syncthreads();
    for (int off = 1; off < 1024; off <<= 1) {
        int v = (tid >= off) ? sums[tid - off] : 0;
        __syncthreads();
        sums[tid] += v;
        __syncthreads();
    }
    int run = (tid == 0) ? 0 : sums[tid - 1];
    for (int i = begin; i < end; ++i) {
        rowptr[i] = run;
        run += cnt[i];
    }
    if (tid == 1023) rowptr[N_] = run;
}

// 3) reorder edges into CSR-by-dst, dinv fused (rsqrt per endpoint).
//    Afterwards rowptr[d]==end(d), start(d)==(d?rowptr[d-1]:0). Packs {src,nw}.
__global__ void reorder_kernel(const int* __restrict__ src, const int* __restrict__ dst,
                               const float* __restrict__ w, const float* __restrict__ degw,
                               int* __restrict__ rowptr, int2* __restrict__ es, int E) {
    int e = blockIdx.x * blockDim.x + threadIdx.x;
    if (e < E) {
        int s = src[e], d = dst[e];
        float ds = degw[s], dd = degw[d];
        float is = ds > 0.f ? rsqrtf(fmaxf(ds, 1e-12f)) : 0.f;
        float id = dd > 0.f ? rsqrtf(fmaxf(dd, 1e-12f)) : 0.f;
        float nwv = -w[e] * is * id;
        int pos = atomicAdd(&rowptr[d], 1);
        es[pos] = make_int2(s, __float_as_int(nwv));
    }
}

// 4) fused: x fp32 -> bf16 (blocks 0..12499) + weight swizzle (blocks 12500..12563)
__global__ __launch_bounds__(256) void xcvt_wprep_kernel(
        const float* __restrict__ x, unsigned short* __restrict__ xb,
        const float* __restrict__ Wz0, const float* __restrict__ Wz1,
        const float* __restrict__ Wh0, const float* __restrict__ Wh1,
        short* __restrict__ swz) {
    if (blockIdx.x < 12500) {
        long long i = ((long long)blockIdx.x * 256 + threadIdx.x) * 8;
        float4 a = *(const float4*)(x + i);
        float4 b = *(const float4*)(x + i + 4);
        bf16x8 o;
        o[0] = f2bf(a.x); o[1] = f2bf(a.y); o[2] = f2bf(a.z); o[3] = f2bf(a.w);
        o[4] = f2bf(b.x); o[5] = f2bf(b.y); o[6] = f2bf(b.z); o[7] = f2bf(b.w);
        *(bf16x8*)(xb + i) = o;
    } else {
        int idx = (blockIdx.x - 12500) * 256 + threadIdx.x;  // < 16384
        int j = idx & 7;
        int lane = (idx >> 3) & 63;
        int kb = (idx >> 9) & 1;
        int c = (idx >> 10) & 3;
        int mat = idx >> 12;
        const float* W = (mat == 0) ? Wz0 : (mat == 1) ? Wz1 : (mat == 2) ? Wh0 : Wh1;
        int k = kb * 32 + (lane >> 4) * 8 + j;
        int n = c * 16 + (lane & 15);
        swz[idx] = f2bf(W[k * 64 + n]);
    }
}

// 5) atomic-free gather, bf16 in/out. lane = t*8 + oct: lane owns channels
//    [oct*8, oct*8+8) of timestep t -> ONE dwordx4 load per edge per lane.
//    k-loop unrolled x2 to keep two scattered loads in flight.
__global__ __launch_bounds__(256) void gather_kernel(const int* __restrict__ rowptr,
        const int2* __restrict__ es, const unsigned short* __restrict__ xb,
        unsigned short* __restrict__ tx1b) {
    int d = blockIdx.x * 4 + (threadIdx.x >> 6);
    int lane = threadIdx.x & 63;
    if (d >= N_) return;
    int t = lane >> 3;    // 0..7
    int oct = lane & 7;   // 0..7
    int start = d ? rowptr[d - 1] : 0;
    int end = rowptr[d];
    float acc[8] = {0.f, 0.f, 0.f, 0.f, 0.f, 0.f, 0.f, 0.f};
    const unsigned short* xbase = xb + (long long)t * N_ * C_ + oct * 8;
    for (int base = start; base < end; base += 64) {
        int m = end - base;
        if (m > 64) m = 64;
        int2 pk = (lane < m) ? es[base + lane] : make_int2(0, 0);
        int k = 0;
        for (; k + 1 < m; k += 2) {
            int s0 = __shfl(pk.x, k);
            float w0 = __int_as_float(__shfl(pk.y, k));
            int s1 = __shfl(pk.x, k + 1);
            float w1 = __int_as_float(__shfl(pk.y, k + 1));
            uint4 v0 = *(const uint4*)(xbase + (long long)s0 * C_);
            uint4 v1 = *(const uint4*)(xbase + (long long)s1 * C_);
            acc[0] += w0 * bf2f_lo(v0.x); acc[1] += w0 * bf2f_hi(v0.x);
            acc[2] += w0 * bf2f_lo(v0.y); acc[3] += w0 * bf2f_hi(v0.y);
            acc[4] += w0 * bf2f_lo(v0.z); acc[5] += w0 * bf2f_hi(v0.z);
            acc[6] += w0 * bf2f_lo(v0.w); acc[7] += w0 * bf2f_hi(v0.w);
            acc[0] += w1 * bf2f_lo(v1.x); acc[1] += w1 * bf2f_hi(v1.x);
            acc[2] += w1 * bf2f_lo(v1.y); acc[3] += w1 * bf2f_hi(v1.y);
            acc[4] += w1 * bf2f_lo(v1.z); acc[5] += w1 * bf2f_hi(v1.z);
            acc[6] += w1 * bf2f_lo(v1.w); acc[7] += w1 * bf2f_hi(v1.w);
        }
        if (k < m) {
            int s0 = __shfl(pk.x, k);
            float w0 = __int_as_float(__shfl(pk.y, k));
            uint4 v0 = *(const uint4*)(xbase + (long long)s0 * C_);
            acc[0] += w0 * bf2f_lo(v0.x); acc[1] += w0 * bf2f_hi(v0.x);
            acc[2] += w0 * bf2f_lo(v0.y); acc[3] += w0 * bf2f_hi(v0.y);
            acc[4] += w0 * bf2f_lo(v0.z); acc[5] += w0 * bf2f_hi(v0.z);
            acc[6] += w0 * bf2f_lo(v0.w); acc[7] += w0 * bf2f_hi(v0.w);
        }
    }
    uint4 o;
    o.x = (unsigned int)(unsigned short)f2bf(acc[0]) |
          ((unsigned int)(unsigned short)f2bf(acc[1]) << 16);
    o.y = (unsigned int)(unsigned short)f2bf(acc[2]) |
          ((unsigned int)(unsigned short)f2bf(acc[3]) << 16);
    o.z = (unsigned int)(unsigned short)f2bf(acc[4]) |
          ((unsigned int)(unsigned short)f2bf(acc[5]) << 16);
    o.w = (unsigned int)(unsigned short)f2bf(acc[6]) |
          ((unsigned int)(unsigned short)f2bf(acc[7]) << 16);
    *(uint4*)(tx1b + ((long long)t * N_ + d) * C_ + oct * 8) = o;
}

// 6) MFMA node kernel: 4 waves/block, 16 rows/wave, 64 rows/block.
__global__ __launch_bounds__(256) void node_kernel(
        const unsigned short* __restrict__ xb, const unsigned short* __restrict__ tx1b,
        const short* __restrict__ swz,
        const float* __restrict__ bxz, const float* __restrict__ bhz,
        const float* __restrict__ bxh, const float* __restrict__ bhh,
        const float* __restrict__ Wlin, const float* __restrict__ blin,
        float* __restrict__ out) {
    __shared__ short lds[4 * 4096];  // 32 KB swizzled bf16 weights

    {
        const int4* s4 = (const int4*)swz;
        int4* l4 = (int4*)lds;
        for (int i = threadIdx.x; i < 2048; i += 256) l4[i] = s4[i];
    }
    __syncthreads();

    int lane = threadIdx.x & 63;
    int wid = threadIdx.x >> 6;
    int c16 = lane & 15;
    int kq = lane >> 4;
    long long row_base = (long long)blockIdx.x * 64 + wid * 16;

    const unsigned short* xr = xb + (row_base + c16) * C_ + kq * 8;
    const unsigned short* tr = tx1b + (row_base + c16) * C_ + kq * 8;
    bf16x8 ax0 = *(const bf16x8*)(xr);
    bf16x8 ax1 = *(const bf16x8*)(xr + 32);
    bf16x8 at0 = *(const bf16x8*)(tr);
    bf16x8 at1 = *(const bf16x8*)(tr + 32);

    f32x4 az[4], ah[4];
#pragma unroll
    for (int c = 0; c < 4; ++c) {
        int col = c * 16 + c16;
        float bz = bxz[col] + bhz[col];
        float bh = bxh[col] + bhh[col];
        az[c] = (f32x4){bz, bz, bz, bz};
        ah[c] = (f32x4){bh, bh, bh, bh};
    }

#pragma unroll
    for (int c = 0; c < 4; ++c) {
        const short* base = lds + lane * 8;
        bf16x8 bz0k0 = *(const bf16x8*)(base + 0 * 4096 + (c * 2 + 0) * 512);
        bf16x8 bz0k1 = *(const bf16x8*)(base + 0 * 4096 + (c * 2 + 1) * 512);
        bf16x8 bz1k0 = *(const bf16x8*)(base + 1 * 4096 + (c * 2 + 0) * 512);
        bf16x8 bz1k1 = *(const bf16x8*)(base + 1 * 4096 + (c * 2 + 1) * 512);
        bf16x8 bh0k0 = *(const bf16x8*)(base + 2 * 4096 + (c * 2 + 0) * 512);
        bf16x8 bh0k1 = *(const bf16x8*)(base + 2 * 4096 + (c * 2 + 1) * 512);
        bf16x8 bh1k0 = *(const bf16x8*)(base + 3 * 4096 + (c * 2 + 0) * 512);
        bf16x8 bh1k1 = *(const bf16x8*)(base + 3 * 4096 + (c * 2 + 1) * 512);
        az[c] = __builtin_amdgcn_mfma_f32_16x16x32_bf16(ax0, bz0k0, az[c], 0, 0, 0);
        az[c] = __builtin_amdgcn_mfma_f32_16x16x32_bf16(ax1, bz0k1, az[c], 0, 0, 0);
        az[c] = __builtin_amdgcn_mfma_f32_16x16x32_bf16(at0, bz1k0, az[c], 0, 0, 0);
        az[c] = __builtin_amdgcn_mfma_f32_16x16x32_bf16(at1, bz1k1, az[c], 0, 0, 0);
        ah[c] = __builtin_amdgcn_mfma_f32_16x16x32_bf16(ax0, bh0k0, ah[c], 0, 0, 0);
        ah[c] = __builtin_amdgcn_mfma_f32_16x16x32_bf16(ax1, bh0k1, ah[c], 0, 0, 0);
        ah[c] = __builtin_amdgcn_mfma_f32_16x16x32_bf16(at0, bh1k0, ah[c], 0, 0, 0);
        ah[c] = __builtin_amdgcn_mfma_f32_16x16x32_bf16(at1, bh1k1, ah[c], 0, 0, 0);
    }

    float part[4] = {0.f, 0.f, 0.f, 0.f};
#pragma unroll
    for (int c = 0; c < 4; ++c) {
        int col = c * 16 + c16;
        float wl = Wlin[col];
#pragma unroll
        for (int r = 0; r < 4; ++r) {
            float a = az[c][r];
            float b = ah[c][r];
            float z = 1.f / (1.f + __expf(-a));
            float aa = fabsf(b);
            float e = __expf(-2.f * aa);
            float ht = copysignf((1.f - e) / (1.f + e), b);
            float h = fmaxf((1.f - z) * ht, 0.f);
            part[r] += h * wl;
        }
    }
#pragma unroll
    for (int m = 1; m <= 8; m <<= 1) {
#pragma unroll
        for (int r = 0; r < 4; ++r) part[r] += __shfl_xor(part[r], m);
    }
    if (c16 == 0) {
        float bl = blin[0];
        long long row = row_base + kq * 4;
#pragma unroll
        for (int r = 0; r < 4; ++r) out[row + r] = part[r] + bl;
    }
}

extern "C" void kernel_launch(void* const* d_in, const int* in_sizes, int n_in,
                              void* d_out, int out_size, void* d_ws, size_t ws_size,
                              hipStream_t stream) {
    const float* x    = (const float*)d_in[0];
    const int*   ei   = (const int*)d_in[1];
    const float* w    = (const float*)d_in[2];
    const float* Wxz0 = (const float*)d_in[3];
    const float* Wxz1 = (const float*)d_in[4];
    const float* bxz  = (const float*)d_in[5];
    const float* bhz  = (const float*)d_in[8];
    const float* Wxh0 = (const float*)d_in[15];
    const float* Wxh1 = (const float*)d_in[16];
    const float* bxh  = (const float*)d_in[17];
    const float* bhh  = (const float*)d_in[20];
    const float* Wlin = (const float*)d_in[21];
    const float* blin = (const float*)d_in[22];
    float* out = (float*)d_out;

    const int* src = ei;
    const int* dst = ei + E_;

    // workspace layout (512-aligned blocks):
    char* ws = (char*)d_ws;
    size_t off = 0;
    auto alloc = [&](size_t bytes) {
        char* p = ws + off;
        off = (off + bytes + 511) & ~(size_t)511;
        return p;
    };
    short* swz             = (short*)alloc(4 * 4096 * sizeof(short));           // 32 KB
    float* degw            = (float*)alloc((size_t)N_ * 4);
    int*   cnt             = (int*)alloc((size_t)N_ * 4);
    int*   rowptr          = (int*)alloc(((size_t)N_ + 1) * 4);
    int2*  es              = (int2*)alloc((size_t)E_ * 8);                      // 6.4 MB
    unsigned short* xb     = (unsigned short*)alloc((size_t)T_ * N_ * C_ * 2);  // 51.2 MB
    unsigned short* tx1b   = (unsigned short*)alloc((size_t)T_ * N_ * C_ * 2);  // 51.2 MB

    hipMemsetAsync(degw, 0, (size_t)N_ * 4, stream);
    hipMemsetAsync(cnt, 0, (size_t)N_ * 4, stream);

    hist_kernel<<<(E_ + 255) / 256, 256, 0, stream>>>(src, dst, w, degw, cnt, E_);
    scan_kernel<<<1, 1024, 0, stream>>>(cnt, rowptr);
    reorder_kernel<<<(E_ + 255) / 256, 256, 0, stream>>>(src, dst, w, degw, rowptr, es, E_);
    xcvt_wprep_kernel<<<12564, 256, 0, stream>>>(x, xb, Wxz0, Wxz1, Wxh0, Wxh1, swz);

    int gather_blocks = (N_ + 3) / 4;
    gather_kernel<<<gather_blocks, 256, 0, stream>>>(rowptr, es, xb, tx1b);

    long long TN = (long long)T_ * N_;
    int node_blocks = (int)(TN / 64);  // 400000 % 64 == 0
    node_kernel<<<node_blocks, 256, 0, stream>>>(
        xb, tx1b, swz, bxz, bhz, bxh, bhh, Wlin, blin, out);
}

// Round 6
// 516.347 us; speedup vs baseline: 6.4905x; 1.0673x over previous
//
#include <hip/hip_runtime.h>

#define T_ 8
#define N_ 50000
#define E_ 800000
#define C_ 64

typedef __attribute__((ext_vector_type(8))) short bf16x8;
typedef __attribute__((ext_vector_type(4))) float f32x4;

__device__ inline short f2bf(float f) {
    union { float f; unsigned int u; } v; v.f = f;
    unsigned int u = v.u + 0x7FFFu + ((v.u >> 16) & 1u);  // RNE
    return (short)(u >> 16);
}
__device__ inline float bf2f_lo(unsigned int u) {
    union { unsigned int u; float f; } v; v.u = u << 16;
    return v.f;
}
__device__ inline float bf2f_hi(unsigned int u) {
    union { unsigned int u; float f; } v; v.u = u & 0xffff0000u;
    return v.f;
}

// ---------------------------------------------------------------------------
// 1) fused: hist (blocks [0,3125)) + xcvt (blocks [3125,15625)) + wprep (rest).
//    hist first: scan depends on cnt, so its atomics start immediately.
__global__ __launch_bounds__(256) void fused_prep_kernel(
        const int* __restrict__ src, const int* __restrict__ dst,
        const float* __restrict__ w,
        float* __restrict__ degw, int* __restrict__ cnt,
        const float* __restrict__ x, unsigned short* __restrict__ xb,
        const float* __restrict__ Wz0, const float* __restrict__ Wz1,
        const float* __restrict__ Wh0, const float* __restrict__ Wh1,
        short* __restrict__ swz) {
    if (blockIdx.x < 3125) {
        int e = blockIdx.x * 256 + threadIdx.x;
        if (e < E_) {
            atomicAdd(&degw[src[e]], w[e]);
            atomicAdd(&cnt[dst[e]], 1);
        }
    } else if (blockIdx.x < 15625) {
        long long i = ((long long)(blockIdx.x - 3125) * 256 + threadIdx.x) * 8;
        float4 a = *(const float4*)(x + i);
        float4 b = *(const float4*)(x + i + 4);
        bf16x8 o;
        o[0] = f2bf(a.x); o[1] = f2bf(a.y); o[2] = f2bf(a.z); o[3] = f2bf(a.w);
        o[4] = f2bf(b.x); o[5] = f2bf(b.y); o[6] = f2bf(b.z); o[7] = f2bf(b.w);
        *(bf16x8*)(xb + i) = o;
    } else {
        int idx = (blockIdx.x - 15625) * 256 + threadIdx.x;  // < 16384
        int j = idx & 7;
        int lane = (idx >> 3) & 63;
        int kb = (idx >> 9) & 1;
        int c = (idx >> 10) & 3;
        int mat = idx >> 12;
        const float* W = (mat == 0) ? Wz0 : (mat == 1) ? Wz1 : (mat == 2) ? Wh0 : Wh1;
        int k = kb * 32 + (lane >> 4) * 8 + j;
        int n = c * 16 + (lane & 15);
        swz[idx] = f2bf(W[k * 64 + n]);
    }
}

// 2) coalesced tiled exclusive scan: 49 tiles x 1024, wave shfl-scan + LDS combine
__global__ __launch_bounds__(1024) void scan_kernel(const int* __restrict__ cnt,
                                                    int* __restrict__ rowptr) {
    __shared__ int wsum[16];
    __shared__ int tile_tot_s;
    int tid = threadIdx.x, lane = tid & 63, wid = tid >> 6;
    int running = 0;
    const int NT = (N_ + 1023) / 1024;  // 49
    for (int tile = 0; tile < NT; ++tile) {
        int idx = tile * 1024 + tid;
        int orig = (idx < N_) ? cnt[idx] : 0;
        int v = orig;
#pragma unroll
        for (int off = 1; off < 64; off <<= 1) {
            int u = __shfl_up(v, off);
            if (lane >= off) v += u;
        }
        if (lane == 63) wsum[wid] = v;
        __syncthreads();
        if (wid == 0) {
            int s = (lane < 16) ? wsum[lane] : 0;
#pragma unroll
            for (int off = 1; off < 16; off <<= 1) {
                int u = __shfl_up(s, off);
                if (lane >= off) s += u;
            }
            if (lane < 16) wsum[lane] = s;  // inclusive over waves
            if (lane == 15) tile_tot_s = s;
        }
        __syncthreads();
        int wpre = wid ? wsum[wid - 1] : 0;
        if (idx < N_) rowptr[idx] = running + wpre + v - orig;
        running += tile_tot_s;
        __syncthreads();  // wsum/tile_tot reused next tile
    }
    if (tid == 0) rowptr[N_] = running;
}

// 3) reorder edges into CSR-by-dst, dinv fused. Afterwards rowptr[d]==end(d),
//    start(d)==(d?rowptr[d-1]:0). Packs {src,nw}.
__global__ void reorder_kernel(const int* __restrict__ src, const int* __restrict__ dst,
                               const float* __restrict__ w, const float* __restrict__ degw,
                               int* __restrict__ rowptr, int2* __restrict__ es, int E) {
    int e = blockIdx.x * blockDim.x + threadIdx.x;
    if (e < E) {
        int s = src[e], d = dst[e];
        float ds = degw[s], dd = degw[d];
        float is = ds > 0.f ? rsqrtf(fmaxf(ds, 1e-12f)) : 0.f;
        float id = dd > 0.f ? rsqrtf(fmaxf(dd, 1e-12f)) : 0.f;
        float nwv = -w[e] * is * id;
        int pos = atomicAdd(&rowptr[d], 1);
        es[pos] = make_int2(s, __float_as_int(nwv));
    }
}

// 4) atomic-free gather, bf16 in/out. lane = t*8 + oct -> one dwordx4/edge/lane.
//    k-loop unrolled x4 for MLP.
__global__ __launch_bounds__(256) void gather_kernel(const int* __restrict__ rowptr,
        const int2* __restrict__ es, const unsigned short* __restrict__ xb,
        unsigned short* __restrict__ tx1b) {
    int d = blockIdx.x * 4 + (threadIdx.x >> 6);
    int lane = threadIdx.x & 63;
    if (d >= N_) return;
    int t = lane >> 3;
    int oct = lane & 7;
    int start = d ? rowptr[d - 1] : 0;
    int end = rowptr[d];
    float acc[8] = {0.f, 0.f, 0.f, 0.f, 0.f, 0.f, 0.f, 0.f};
    const unsigned short* xbase = xb + (long long)t * N_ * C_ + oct * 8;
    for (int base = start; base < end; base += 64) {
        int m = end - base;
        if (m > 64) m = 64;
        int2 pk = (lane < m) ? es[base + lane] : make_int2(0, 0);
        int k = 0;
        for (; k + 3 < m; k += 4) {
            int s0 = __shfl(pk.x, k);
            float w0 = __int_as_float(__shfl(pk.y, k));
            int s1 = __shfl(pk.x, k + 1);
            float w1 = __int_as_float(__shfl(pk.y, k + 1));
            int s2 = __shfl(pk.x, k + 2);
            float w2 = __int_as_float(__shfl(pk.y, k + 2));
            int s3 = __shfl(pk.x, k + 3);
            float w3 = __int_as_float(__shfl(pk.y, k + 3));
            uint4 v0 = *(const uint4*)(xbase + (long long)s0 * C_);
            uint4 v1 = *(const uint4*)(xbase + (long long)s1 * C_);
            uint4 v2 = *(const uint4*)(xbase + (long long)s2 * C_);
            uint4 v3 = *(const uint4*)(xbase + (long long)s3 * C_);
            acc[0] += w0 * bf2f_lo(v0.x); acc[1] += w0 * bf2f_hi(v0.x);
            acc[2] += w0 * bf2f_lo(v0.y); acc[3] += w0 * bf2f_hi(v0.y);
            acc[4] += w0 * bf2f_lo(v0.z); acc[5] += w0 * bf2f_hi(v0.z);
            acc[6] += w0 * bf2f_lo(v0.w); acc[7] += w0 * bf2f_hi(v0.w);
            acc[0] += w1 * bf2f_lo(v1.x); acc[1] += w1 * bf2f_hi(v1.x);
            acc[2] += w1 * bf2f_lo(v1.y); acc[3] += w1 * bf2f_hi(v1.y);
            acc[4] += w1 * bf2f_lo(v1.z); acc[5] += w1 * bf2f_hi(v1.z);
            acc[6] += w1 * bf2f_lo(v1.w); acc[7] += w1 * bf2f_hi(v1.w);
            acc[0] += w2 * bf2f_lo(v2.x); acc[1] += w2 * bf2f_hi(v2.x);
            acc[2] += w2 * bf2f_lo(v2.y); acc[3] += w2 * bf2f_hi(v2.y);
            acc[4] += w2 * bf2f_lo(v2.z); acc[5] += w2 * bf2f_hi(v2.z);
            acc[6] += w2 * bf2f_lo(v2.w); acc[7] += w2 * bf2f_hi(v2.w);
            acc[0] += w3 * bf2f_lo(v3.x); acc[1] += w3 * bf2f_hi(v3.x);
            acc[2] += w3 * bf2f_lo(v3.y); acc[3] += w3 * bf2f_hi(v3.y);
            acc[4] += w3 * bf2f_lo(v3.z); acc[5] += w3 * bf2f_hi(v3.z);
            acc[6] += w3 * bf2f_lo(v3.w); acc[7] += w3 * bf2f_hi(v3.w);
        }
        for (; k < m; ++k) {
            int s0 = __shfl(pk.x, k);
            float w0 = __int_as_float(__shfl(pk.y, k));
            uint4 v0 = *(const uint4*)(xbase + (long long)s0 * C_);
            acc[0] += w0 * bf2f_lo(v0.x); acc[1] += w0 * bf2f_hi(v0.x);
            acc[2] += w0 * bf2f_lo(v0.y); acc[3] += w0 * bf2f_hi(v0.y);
            acc[4] += w0 * bf2f_lo(v0.z); acc[5] += w0 * bf2f_hi(v0.z);
            acc[6] += w0 * bf2f_lo(v0.w); acc[7] += w0 * bf2f_hi(v0.w);
        }
    }
    uint4 o;
    o.x = (unsigned int)(unsigned short)f2bf(acc[0]) |
          ((unsigned int)(unsigned short)f2bf(acc[1]) << 16);
    o.y = (unsigned int)(unsigned short)f2bf(acc[2]) |
          ((unsigned int)(unsigned short)f2bf(acc[3]) << 16);
    o.z = (unsigned int)(unsigned short)f2bf(acc[4]) |
          ((unsigned int)(unsigned short)f2bf(acc[5]) << 16);
    o.w = (unsigned int)(unsigned short)f2bf(acc[6]) |
          ((unsigned int)(unsigned short)f2bf(acc[7]) << 16);
    *(uint4*)(tx1b + ((long long)t * N_ + d) * C_ + oct * 8) = o;
}

// 5) MFMA node kernel: 4 waves/block, 16 rows/wave, 64 rows/tile,
//    ~8 tiles per block so the 32 KB swz LDS stage is amortized.
__global__ __launch_bounds__(256) void node_kernel(
        const unsigned short* __restrict__ xb, const unsigned short* __restrict__ tx1b,
        const short* __restrict__ swz,
        const float* __restrict__ bxz, const float* __restrict__ bhz,
        const float* __restrict__ bxh, const float* __restrict__ bhh,
        const float* __restrict__ Wlin, const float* __restrict__ blin,
        float* __restrict__ out, int n_tiles) {
    __shared__ short lds[4 * 4096];  // 32 KB swizzled bf16 weights

    {
        const int4* s4 = (const int4*)swz;
        int4* l4 = (int4*)lds;
        for (int i = threadIdx.x; i < 2048; i += 256) l4[i] = s4[i];
    }
    __syncthreads();

    int lane = threadIdx.x & 63;
    int wid = threadIdx.x >> 6;
    int c16 = lane & 15;
    int kq = lane >> 4;
    float bl = blin[0];

    for (int tile = blockIdx.x; tile < n_tiles; tile += gridDim.x) {
        long long row_base = (long long)tile * 64 + wid * 16;

        const unsigned short* xr = xb + (row_base + c16) * C_ + kq * 8;
        const unsigned short* tr = tx1b + (row_base + c16) * C_ + kq * 8;
        bf16x8 ax0 = *(const bf16x8*)(xr);
        bf16x8 ax1 = *(const bf16x8*)(xr + 32);
        bf16x8 at0 = *(const bf16x8*)(tr);
        bf16x8 at1 = *(const bf16x8*)(tr + 32);

        f32x4 az[4], ah[4];
#pragma unroll
        for (int c = 0; c < 4; ++c) {
            int col = c * 16 + c16;
            float bz = bxz[col] + bhz[col];
            float bh = bxh[col] + bhh[col];
            az[c] = (f32x4){bz, bz, bz, bz};
            ah[c] = (f32x4){bh, bh, bh, bh};
        }

#pragma unroll
        for (int c = 0; c < 4; ++c) {
            const short* base = lds + lane * 8;
            bf16x8 bz0k0 = *(const bf16x8*)(base + 0 * 4096 + (c * 2 + 0) * 512);
            bf16x8 bz0k1 = *(const bf16x8*)(base + 0 * 4096 + (c * 2 + 1) * 512);
            bf16x8 bz1k0 = *(const bf16x8*)(base + 1 * 4096 + (c * 2 + 0) * 512);
            bf16x8 bz1k1 = *(const bf16x8*)(base + 1 * 4096 + (c * 2 + 1) * 512);
            bf16x8 bh0k0 = *(const bf16x8*)(base + 2 * 4096 + (c * 2 + 0) * 512);
            bf16x8 bh0k1 = *(const bf16x8*)(base + 2 * 4096 + (c * 2 + 1) * 512);
            bf16x8 bh1k0 = *(const bf16x8*)(base + 3 * 4096 + (c * 2 + 0) * 512);
            bf16x8 bh1k1 = *(const bf16x8*)(base + 3 * 4096 + (c * 2 + 1) * 512);
            az[c] = __builtin_amdgcn_mfma_f32_16x16x32_bf16(ax0, bz0k0, az[c], 0, 0, 0);
            az[c] = __builtin_amdgcn_mfma_f32_16x16x32_bf16(ax1, bz0k1, az[c], 0, 0, 0);
            az[c] = __builtin_amdgcn_mfma_f32_16x16x32_bf16(at0, bz1k0, az[c], 0, 0, 0);
            az[c] = __builtin_amdgcn_mfma_f32_16x16x32_bf16(at1, bz1k1, az[c], 0, 0, 0);
            ah[c] = __builtin_amdgcn_mfma_f32_16x16x32_bf16(ax0, bh0k0, ah[c], 0, 0, 0);
            ah[c] = __builtin_amdgcn_mfma_f32_16x16x32_bf16(ax1, bh0k1, ah[c], 0, 0, 0);
            ah[c] = __builtin_amdgcn_mfma_f32_16x16x32_bf16(at0, bh1k0, ah[c], 0, 0, 0);
            ah[c] = __builtin_amdgcn_mfma_f32_16x16x32_bf16(at1, bh1k1, ah[c], 0, 0, 0);
        }

        float part[4] = {0.f, 0.f, 0.f, 0.f};
#pragma unroll
        for (int c = 0; c < 4; ++c) {
            int col = c * 16 + c16;
            float wl = Wlin[col];
#pragma unroll
            for (int r = 0; r < 4; ++r) {
                float a = az[c][r];
                float b = ah[c][r];
                float z = 1.f / (1.f + __expf(-a));
                float aa = fabsf(b);
                float e = __expf(-2.f * aa);
                float ht = copysignf((1.f - e) / (1.f + e), b);
                float h = fmaxf((1.f - z) * ht, 0.f);
                part[r] += h * wl;
            }
        }
#pragma unroll
        for (int m = 1; m <= 8; m <<= 1) {
#pragma unroll
            for (int r = 0; r < 4; ++r) part[r] += __shfl_xor(part[r], m);
        }
        if (c16 == 0) {
            long long row = row_base + kq * 4;
#pragma unroll
            for (int r = 0; r < 4; ++r) out[row + r] = part[r] + bl;
        }
    }
}

extern "C" void kernel_launch(void* const* d_in, const int* in_sizes, int n_in,
                              void* d_out, int out_size, void* d_ws, size_t ws_size,
                              hipStream_t stream) {
    const float* x    = (const float*)d_in[0];
    const int*   ei   = (const int*)d_in[1];
    const float* w    = (const float*)d_in[2];
    const float* Wxz0 = (const float*)d_in[3];
    const float* Wxz1 = (const float*)d_in[4];
    const float* bxz  = (const float*)d_in[5];
    const float* bhz  = (const float*)d_in[8];
    const float* Wxh0 = (const float*)d_in[15];
    const float* Wxh1 = (const float*)d_in[16];
    const float* bxh  = (const float*)d_in[17];
    const float* bhh  = (const float*)d_in[20];
    const float* Wlin = (const float*)d_in[21];
    const float* blin = (const float*)d_in[22];
    float* out = (float*)d_out;

    const int* src = ei;
    const int* dst = ei + E_;

    // workspace layout (512-aligned blocks):
    char* ws = (char*)d_ws;
    size_t off = 0;
    auto alloc = [&](size_t bytes) {
        char* p = ws + off;
        off = (off + bytes + 511) & ~(size_t)511;
        return p;
    };
    short* swz             = (short*)alloc(4 * 4096 * sizeof(short));           // 32 KB
    float* degw            = (float*)alloc((size_t)N_ * 4);
    int*   cnt             = (int*)alloc((size_t)N_ * 4);
    int*   rowptr          = (int*)alloc(((size_t)N_ + 1) * 4);
    int2*  es              = (int2*)alloc((size_t)E_ * 8);                      // 6.4 MB
    unsigned short* xb     = (unsigned short*)alloc((size_t)T_ * N_ * C_ * 2);  // 51.2 MB
    unsigned short* tx1b   = (unsigned short*)alloc((size_t)T_ * N_ * C_ * 2);  // 51.2 MB

    hipMemsetAsync(degw, 0, (size_t)N_ * 4, stream);
    hipMemsetAsync(cnt, 0, (size_t)N_ * 4, stream);

    // hist (3125) + xcvt (12500) + wprep (64) = 15689 blocks
    fused_prep_kernel<<<15689, 256, 0, stream>>>(src, dst, w, degw, cnt,
                                                 x, xb, Wxz0, Wxz1, Wxh0, Wxh1, swz);
    scan_kernel<<<1, 1024, 0, stream>>>(cnt, rowptr);
    reorder_kernel<<<(E_ + 255) / 256, 256, 0, stream>>>(src, dst, w, degw, rowptr, es, E_);

    int gather_blocks = (N_ + 3) / 4;
    gather_kernel<<<gather_blocks, 256, 0, stream>>>(rowptr, es, xb, tx1b);

    int n_tiles = (int)((long long)T_ * N_ / 64);  // 6250
    node_kernel<<<782, 256, 0, stream>>>(
        xb, tx1b, swz, bxz, bhz, bxh, bhh, Wlin, blin, out, n_tiles);
}

// Round 7
// 476.149 us; speedup vs baseline: 7.0384x; 1.0844x over previous
//
#include <hip/hip_runtime.h>

#define T_ 8
#define N_ 50000
#define E_ 800000
#define C_ 64

typedef __attribute__((ext_vector_type(8))) short bf16x8;
typedef __attribute__((ext_vector_type(4))) float f32x4;

__device__ inline short f2bf(float f) {
    union { float f; unsigned int u; } v; v.f = f;
    unsigned int u = v.u + 0x7FFFu + ((v.u >> 16) & 1u);  // RNE
    return (short)(u >> 16);
}
__device__ inline float bf2f_lo(unsigned int u) {
    union { unsigned int u; float f; } v; v.u = u << 16;
    return v.f;
}
__device__ inline float bf2f_hi(unsigned int u) {
    union { unsigned int u; float f; } v; v.u = u & 0xffff0000u;
    return v.f;
}

#define SCAN_TILES 49  // ceil(N / 1024)

// ---------------------------------------------------------------------------
// 1) fused: hist (blocks [0,3125)) + xcvt (blocks [3125,15625)) + wprep (rest)
__global__ __launch_bounds__(256) void fused_prep_kernel(
        const int* __restrict__ src, const int* __restrict__ dst,
        const float* __restrict__ w,
        float* __restrict__ degw, int* __restrict__ cnt,
        const float* __restrict__ x, unsigned short* __restrict__ xb,
        const float* __restrict__ Wz0, const float* __restrict__ Wz1,
        const float* __restrict__ Wh0, const float* __restrict__ Wh1,
        short* __restrict__ swz) {
    if (blockIdx.x < 3125) {
        int e = blockIdx.x * 256 + threadIdx.x;
        if (e < E_) {
            atomicAdd(&degw[src[e]], w[e]);
            atomicAdd(&cnt[dst[e]], 1);
        }
    } else if (blockIdx.x < 15625) {
        long long i = ((long long)(blockIdx.x - 3125) * 256 + threadIdx.x) * 8;
        float4 a = *(const float4*)(x + i);
        float4 b = *(const float4*)(x + i + 4);
        bf16x8 o;
        o[0] = f2bf(a.x); o[1] = f2bf(a.y); o[2] = f2bf(a.z); o[3] = f2bf(a.w);
        o[4] = f2bf(b.x); o[5] = f2bf(b.y); o[6] = f2bf(b.z); o[7] = f2bf(b.w);
        *(bf16x8*)(xb + i) = o;
    } else {
        int idx = (blockIdx.x - 15625) * 256 + threadIdx.x;  // < 16384
        int j = idx & 7;
        int lane = (idx >> 3) & 63;
        int kb = (idx >> 9) & 1;
        int c = (idx >> 10) & 3;
        int mat = idx >> 12;
        const float* W = (mat == 0) ? Wz0 : (mat == 1) ? Wz1 : (mat == 2) ? Wh0 : Wh1;
        int k = kb * 32 + (lane >> 4) * 8 + j;
        int n = c * 16 + (lane & 15);
        swz[idx] = f2bf(W[k * 64 + n]);
    }
}

// 2a) parallel scan pass A: per-tile exclusive scan (no global offset) + tile totals
__global__ __launch_bounds__(1024) void scan_a_kernel(const int* __restrict__ cnt,
                                                      int* __restrict__ rowptr,
                                                      int* __restrict__ tsum) {
    __shared__ int wsum[16];
    int tid = threadIdx.x, lane = tid & 63, wid = tid >> 6;
    int idx = blockIdx.x * 1024 + tid;
    int orig = (idx < N_) ? cnt[idx] : 0;
    int v = orig;
#pragma unroll
    for (int off = 1; off < 64; off <<= 1) {
        int u = __shfl_up(v, off);
        if (lane >= off) v += u;
    }
    if (lane == 63) wsum[wid] = v;
    __syncthreads();
    if (wid == 0) {
        int s = (lane < 16) ? wsum[lane] : 0;
#pragma unroll
        for (int off = 1; off < 16; off <<= 1) {
            int u = __shfl_up(s, off);
            if (lane >= off) s += u;
        }
        if (lane < 16) wsum[lane] = s;
    }
    __syncthreads();
    int wpre = wid ? wsum[wid - 1] : 0;
    if (idx < N_) rowptr[idx] = wpre + v - orig;
    if (tid == 0) tsum[blockIdx.x] = wsum[15];
}

// 2b) pass B: every block redundantly scans the 49 tile totals, adds its offset
__global__ __launch_bounds__(1024) void scan_b_kernel(const int* __restrict__ tsum,
                                                      int* __restrict__ rowptr) {
    __shared__ int soff[SCAN_TILES];
    __shared__ int stot;
    int tid = threadIdx.x, lane = tid & 63, wid = tid >> 6;
    if (wid == 0) {
        int own = (lane < SCAN_TILES) ? tsum[lane] : 0;
        int s = own;
#pragma unroll
        for (int off = 1; off < 64; off <<= 1) {
            int u = __shfl_up(s, off);
            if (lane >= off) s += u;
        }
        if (lane < SCAN_TILES) soff[lane] = s - own;  // exclusive
        if (lane == SCAN_TILES - 1) stot = s;
    }
    __syncthreads();
    int off = soff[blockIdx.x];
    int idx = blockIdx.x * 1024 + tid;
    if (idx < N_) rowptr[idx] += off;
    if (blockIdx.x == SCAN_TILES - 1 && tid == 0) rowptr[N_] = stot;
}

// 3) reorder edges into CSR-by-dst, dinv fused. Afterwards rowptr[d]==end(d),
//    start(d)==(d?rowptr[d-1]:0). Packs {src,nw}.
__global__ void reorder_kernel(const int* __restrict__ src, const int* __restrict__ dst,
                               const float* __restrict__ w, const float* __restrict__ degw,
                               int* __restrict__ rowptr, int2* __restrict__ es, int E) {
    int e = blockIdx.x * blockDim.x + threadIdx.x;
    if (e < E) {
        int s = src[e], d = dst[e];
        float ds = degw[s], dd = degw[d];
        float is = ds > 0.f ? rsqrtf(fmaxf(ds, 1e-12f)) : 0.f;
        float id = dd > 0.f ? rsqrtf(fmaxf(dd, 1e-12f)) : 0.f;
        float nwv = -w[e] * is * id;
        int pos = atomicAdd(&rowptr[d], 1);
        es[pos] = make_int2(s, __float_as_int(nwv));
    }
}

// 4) atomic-free gather, bf16 in/out. lane = t*8 + oct -> one dwordx4/edge/lane.
__global__ __launch_bounds__(256) void gather_kernel(const int* __restrict__ rowptr,
        const int2* __restrict__ es, const unsigned short* __restrict__ xb,
        unsigned short* __restrict__ tx1b) {
    int d = blockIdx.x * 4 + (threadIdx.x >> 6);
    int lane = threadIdx.x & 63;
    if (d >= N_) return;
    int t = lane >> 3;
    int oct = lane & 7;
    int start = d ? rowptr[d - 1] : 0;
    int end = rowptr[d];
    float acc[8] = {0.f, 0.f, 0.f, 0.f, 0.f, 0.f, 0.f, 0.f};
    const unsigned short* xbase = xb + (long long)t * N_ * C_ + oct * 8;
    for (int base = start; base < end; base += 64) {
        int m = end - base;
        if (m > 64) m = 64;
        int2 pk = (lane < m) ? es[base + lane] : make_int2(0, 0);
        int k = 0;
        for (; k + 3 < m; k += 4) {
            int s0 = __shfl(pk.x, k);
            float w0 = __int_as_float(__shfl(pk.y, k));
            int s1 = __shfl(pk.x, k + 1);
            float w1 = __int_as_float(__shfl(pk.y, k + 1));
            int s2 = __shfl(pk.x, k + 2);
            float w2 = __int_as_float(__shfl(pk.y, k + 2));
            int s3 = __shfl(pk.x, k + 3);
            float w3 = __int_as_float(__shfl(pk.y, k + 3));
            uint4 v0 = *(const uint4*)(xbase + (long long)s0 * C_);
            uint4 v1 = *(const uint4*)(xbase + (long long)s1 * C_);
            uint4 v2 = *(const uint4*)(xbase + (long long)s2 * C_);
            uint4 v3 = *(const uint4*)(xbase + (long long)s3 * C_);
            acc[0] += w0 * bf2f_lo(v0.x); acc[1] += w0 * bf2f_hi(v0.x);
            acc[2] += w0 * bf2f_lo(v0.y); acc[3] += w0 * bf2f_hi(v0.y);
            acc[4] += w0 * bf2f_lo(v0.z); acc[5] += w0 * bf2f_hi(v0.z);
            acc[6] += w0 * bf2f_lo(v0.w); acc[7] += w0 * bf2f_hi(v0.w);
            acc[0] += w1 * bf2f_lo(v1.x); acc[1] += w1 * bf2f_hi(v1.x);
            acc[2] += w1 * bf2f_lo(v1.y); acc[3] += w1 * bf2f_hi(v1.y);
            acc[4] += w1 * bf2f_lo(v1.z); acc[5] += w1 * bf2f_hi(v1.z);
            acc[6] += w1 * bf2f_lo(v1.w); acc[7] += w1 * bf2f_hi(v1.w);
            acc[0] += w2 * bf2f_lo(v2.x); acc[1] += w2 * bf2f_hi(v2.x);
            acc[2] += w2 * bf2f_lo(v2.y); acc[3] += w2 * bf2f_hi(v2.y);
            acc[4] += w2 * bf2f_lo(v2.z); acc[5] += w2 * bf2f_hi(v2.z);
            acc[6] += w2 * bf2f_lo(v2.w); acc[7] += w2 * bf2f_hi(v2.w);
            acc[0] += w3 * bf2f_lo(v3.x); acc[1] += w3 * bf2f_hi(v3.x);
            acc[2] += w3 * bf2f_lo(v3.y); acc[3] += w3 * bf2f_hi(v3.y);
            acc[4] += w3 * bf2f_lo(v3.z); acc[5] += w3 * bf2f_hi(v3.z);
            acc[6] += w3 * bf2f_lo(v3.w); acc[7] += w3 * bf2f_hi(v3.w);
        }
        for (; k < m; ++k) {
            int s0 = __shfl(pk.x, k);
            float w0 = __int_as_float(__shfl(pk.y, k));
            uint4 v0 = *(const uint4*)(xbase + (long long)s0 * C_);
            acc[0] += w0 * bf2f_lo(v0.x); acc[1] += w0 * bf2f_hi(v0.x);
            acc[2] += w0 * bf2f_lo(v0.y); acc[3] += w0 * bf2f_hi(v0.y);
            acc[4] += w0 * bf2f_lo(v0.z); acc[5] += w0 * bf2f_hi(v0.z);
            acc[6] += w0 * bf2f_lo(v0.w); acc[7] += w0 * bf2f_hi(v0.w);
        }
    }
    uint4 o;
    o.x = (unsigned int)(unsigned short)f2bf(acc[0]) |
          ((unsigned int)(unsigned short)f2bf(acc[1]) << 16);
    o.y = (unsigned int)(unsigned short)f2bf(acc[2]) |
          ((unsigned int)(unsigned short)f2bf(acc[3]) << 16);
    o.z = (unsigned int)(unsigned short)f2bf(acc[4]) |
          ((unsigned int)(unsigned short)f2bf(acc[5]) << 16);
    o.w = (unsigned int)(unsigned short)f2bf(acc[6]) |
          ((unsigned int)(unsigned short)f2bf(acc[7]) << 16);
    *(uint4*)(tx1b + ((long long)t * N_ + d) * C_ + oct * 8) = o;
}

// 5) MFMA node kernel: 4 waves/block, 16 rows/wave, 64 rows/tile, multi-tile
__global__ __launch_bounds__(256) void node_kernel(
        const unsigned short* __restrict__ xb, const unsigned short* __restrict__ tx1b,
        const short* __restrict__ swz,
        const float* __restrict__ bxz, const float* __restrict__ bhz,
        const float* __restrict__ bxh, const float* __restrict__ bhh,
        const float* __restrict__ Wlin, const float* __restrict__ blin,
        float* __restrict__ out, int n_tiles) {
    __shared__ short lds[4 * 4096];  // 32 KB swizzled bf16 weights

    {
        const int4* s4 = (const int4*)swz;
        int4* l4 = (int4*)lds;
        for (int i = threadIdx.x; i < 2048; i += 256) l4[i] = s4[i];
    }
    __syncthreads();

    int lane = threadIdx.x & 63;
    int wid = threadIdx.x >> 6;
    int c16 = lane & 15;
    int kq = lane >> 4;
    float bl = blin[0];

    for (int tile = blockIdx.x; tile < n_tiles; tile += gridDim.x) {
        long long row_base = (long long)tile * 64 + wid * 16;

        const unsigned short* xr = xb + (row_base + c16) * C_ + kq * 8;
        const unsigned short* tr = tx1b + (row_base + c16) * C_ + kq * 8;
        bf16x8 ax0 = *(const bf16x8*)(xr);
        bf16x8 ax1 = *(const bf16x8*)(xr + 32);
        bf16x8 at0 = *(const bf16x8*)(tr);
        bf16x8 at1 = *(const bf16x8*)(tr + 32);

        f32x4 az[4], ah[4];
#pragma unroll
        for (int c = 0; c < 4; ++c) {
            int col = c * 16 + c16;
            float bz = bxz[col] + bhz[col];
            float bh = bxh[col] + bhh[col];
            az[c] = (f32x4){bz, bz, bz, bz};
            ah[c] = (f32x4){bh, bh, bh, bh};
        }

#pragma unroll
        for (int c = 0; c < 4; ++c) {
            const short* base = lds + lane * 8;
            bf16x8 bz0k0 = *(const bf16x8*)(base + 0 * 4096 + (c * 2 + 0) * 512);
            bf16x8 bz0k1 = *(const bf16x8*)(base + 0 * 4096 + (c * 2 + 1) * 512);
            bf16x8 bz1k0 = *(const bf16x8*)(base + 1 * 4096 + (c * 2 + 0) * 512);
            bf16x8 bz1k1 = *(const bf16x8*)(base + 1 * 4096 + (c * 2 + 1) * 512);
            bf16x8 bh0k0 = *(const bf16x8*)(base + 2 * 4096 + (c * 2 + 0) * 512);
            bf16x8 bh0k1 = *(const bf16x8*)(base + 2 * 4096 + (c * 2 + 1) * 512);
            bf16x8 bh1k0 = *(const bf16x8*)(base + 3 * 4096 + (c * 2 + 0) * 512);
            bf16x8 bh1k1 = *(const bf16x8*)(base + 3 * 4096 + (c * 2 + 1) * 512);
            az[c] = __builtin_amdgcn_mfma_f32_16x16x32_bf16(ax0, bz0k0, az[c], 0, 0, 0);
            az[c] = __builtin_amdgcn_mfma_f32_16x16x32_bf16(ax1, bz0k1, az[c], 0, 0, 0);
            az[c] = __builtin_amdgcn_mfma_f32_16x16x32_bf16(at0, bz1k0, az[c], 0, 0, 0);
            az[c] = __builtin_amdgcn_mfma_f32_16x16x32_bf16(at1, bz1k1, az[c], 0, 0, 0);
            ah[c] = __builtin_amdgcn_mfma_f32_16x16x32_bf16(ax0, bh0k0, ah[c], 0, 0, 0);
            ah[c] = __builtin_amdgcn_mfma_f32_16x16x32_bf16(ax1, bh0k1, ah[c], 0, 0, 0);
            ah[c] = __builtin_amdgcn_mfma_f32_16x16x32_bf16(at0, bh1k0, ah[c], 0, 0, 0);
            ah[c] = __builtin_amdgcn_mfma_f32_16x16x32_bf16(at1, bh1k1, ah[c], 0, 0, 0);
        }

        float part[4] = {0.f, 0.f, 0.f, 0.f};
#pragma unroll
        for (int c = 0; c < 4; ++c) {
            int col = c * 16 + c16;
            float wl = Wlin[col];
#pragma unroll
            for (int r = 0; r < 4; ++r) {
                float a = az[c][r];
                float b = ah[c][r];
                float z = 1.f / (1.f + __expf(-a));
                float aa = fabsf(b);
                float e = __expf(-2.f * aa);
                float ht = copysignf((1.f - e) / (1.f + e), b);
                float h = fmaxf((1.f - z) * ht, 0.f);
                part[r] += h * wl;
            }
        }
#pragma unroll
        for (int m = 1; m <= 8; m <<= 1) {
#pragma unroll
            for (int r = 0; r < 4; ++r) part[r] += __shfl_xor(part[r], m);
        }
        if (c16 == 0) {
            long long row = row_base + kq * 4;
#pragma unroll
            for (int r = 0; r < 4; ++r) out[row + r] = part[r] + bl;
        }
    }
}

extern "C" void kernel_launch(void* const* d_in, const int* in_sizes, int n_in,
                              void* d_out, int out_size, void* d_ws, size_t ws_size,
                              hipStream_t stream) {
    const float* x    = (const float*)d_in[0];
    const int*   ei   = (const int*)d_in[1];
    const float* w    = (const float*)d_in[2];
    const float* Wxz0 = (const float*)d_in[3];
    const float* Wxz1 = (const float*)d_in[4];
    const float* bxz  = (const float*)d_in[5];
    const float* bhz  = (const float*)d_in[8];
    const float* Wxh0 = (const float*)d_in[15];
    const float* Wxh1 = (const float*)d_in[16];
    const float* bxh  = (const float*)d_in[17];
    const float* bhh  = (const float*)d_in[20];
    const float* Wlin = (const float*)d_in[21];
    const float* blin = (const float*)d_in[22];
    float* out = (float*)d_out;

    const int* src = ei;
    const int* dst = ei + E_;

    // workspace layout (512-aligned blocks):
    char* ws = (char*)d_ws;
    size_t off = 0;
    auto alloc = [&](size_t bytes) {
        char* p = ws + off;
        off = (off + bytes + 511) & ~(size_t)511;
        return p;
    };
    short* swz             = (short*)alloc(4 * 4096 * sizeof(short));           // 32 KB
    float* degw            = (float*)alloc((size_t)N_ * 4);
    int*   cnt             = (int*)alloc((size_t)N_ * 4);
    int*   rowptr          = (int*)alloc(((size_t)N_ + 1) * 4);
    int*   tsum            = (int*)alloc((size_t)SCAN_TILES * 4);
    int2*  es              = (int2*)alloc((size_t)E_ * 8);                      // 6.4 MB
    unsigned short* xb     = (unsigned short*)alloc((size_t)T_ * N_ * C_ * 2);  // 51.2 MB
    unsigned short* tx1b   = (unsigned short*)alloc((size_t)T_ * N_ * C_ * 2);  // 51.2 MB

    hipMemsetAsync(degw, 0, (size_t)N_ * 4, stream);
    hipMemsetAsync(cnt, 0, (size_t)N_ * 4, stream);

    // hist (3125) + xcvt (12500) + wprep (64) = 15689 blocks
    fused_prep_kernel<<<15689, 256, 0, stream>>>(src, dst, w, degw, cnt,
                                                 x, xb, Wxz0, Wxz1, Wxh0, Wxh1, swz);
    scan_a_kernel<<<SCAN_TILES, 1024, 0, stream>>>(cnt, rowptr, tsum);
    scan_b_kernel<<<SCAN_TILES, 1024, 0, stream>>>(tsum, rowptr);
    reorder_kernel<<<(E_ + 255) / 256, 256, 0, stream>>>(src, dst, w, degw, rowptr, es, E_);

    int gather_blocks = (N_ + 3) / 4;
    gather_kernel<<<gather_blocks, 256, 0, stream>>>(rowptr, es, xb, tx1b);

    int n_tiles = (int)((long long)T_ * N_ / 64);  // 6250
    node_kernel<<<782, 256, 0, stream>>>(
        xb, tx1b, swz, bxz, bhz, bxh, bhh, Wlin, blin, out, n_tiles);
}

// Round 8
// 435.012 us; speedup vs baseline: 7.7040x; 1.0946x over previous
//
#include <hip/hip_runtime.h>

#define T_ 8
#define N_ 50000
#define E_ 800000
#define C_ 64

typedef __attribute__((ext_vector_type(8))) short bf16x8;
typedef __attribute__((ext_vector_type(4))) float f32x4;

__device__ inline short f2bf(float f) {
    union { float f; unsigned int u; } v; v.f = f;
    unsigned int u = v.u + 0x7FFFu + ((v.u >> 16) & 1u);  // RNE
    return (short)(u >> 16);
}
__device__ inline float bf2f_lo(unsigned int u) {
    union { unsigned int u; float f; } v; v.u = u << 16;
    return v.f;
}
__device__ inline float bf2f_hi(unsigned int u) {
    union { unsigned int u; float f; } v; v.u = u & 0xffff0000u;
    return v.f;
}

#define SCAN_TILES 49  // ceil(N / 1024)

// ---------------------------------------------------------------------------
// 1) fused: hist (blocks [0,3125)) + xcvt (blocks [3125,15625)) + wprep (rest)
__global__ __launch_bounds__(256) void fused_prep_kernel(
        const int* __restrict__ src, const int* __restrict__ dst,
        const float* __restrict__ w,
        float* __restrict__ degw, int* __restrict__ cnt,
        const float* __restrict__ x, unsigned short* __restrict__ xb,
        const float* __restrict__ Wz0, const float* __restrict__ Wz1,
        const float* __restrict__ Wh0, const float* __restrict__ Wh1,
        short* __restrict__ swz) {
    if (blockIdx.x < 3125) {
        int e = blockIdx.x * 256 + threadIdx.x;
        if (e < E_) {
            atomicAdd(&degw[src[e]], w[e]);
            atomicAdd(&cnt[dst[e]], 1);
        }
    } else if (blockIdx.x < 15625) {
        long long i = ((long long)(blockIdx.x - 3125) * 256 + threadIdx.x) * 8;
        float4 a = *(const float4*)(x + i);
        float4 b = *(const float4*)(x + i + 4);
        bf16x8 o;
        o[0] = f2bf(a.x); o[1] = f2bf(a.y); o[2] = f2bf(a.z); o[3] = f2bf(a.w);
        o[4] = f2bf(b.x); o[5] = f2bf(b.y); o[6] = f2bf(b.z); o[7] = f2bf(b.w);
        *(bf16x8*)(xb + i) = o;
    } else {
        int idx = (blockIdx.x - 15625) * 256 + threadIdx.x;  // < 16384
        int j = idx & 7;
        int lane = (idx >> 3) & 63;
        int kb = (idx >> 9) & 1;
        int c = (idx >> 10) & 3;
        int mat = idx >> 12;
        const float* W = (mat == 0) ? Wz0 : (mat == 1) ? Wz1 : (mat == 2) ? Wh0 : Wh1;
        int k = kb * 32 + (lane >> 4) * 8 + j;
        int n = c * 16 + (lane & 15);
        swz[idx] = f2bf(W[k * 64 + n]);
    }
}

// 2a) parallel scan pass A: per-tile exclusive scan + tile totals
__global__ __launch_bounds__(1024) void scan_a_kernel(const int* __restrict__ cnt,
                                                      int* __restrict__ rowptr,
                                                      int* __restrict__ tsum) {
    __shared__ int wsum[16];
    int tid = threadIdx.x, lane = tid & 63, wid = tid >> 6;
    int idx = blockIdx.x * 1024 + tid;
    int orig = (idx < N_) ? cnt[idx] : 0;
    int v = orig;
#pragma unroll
    for (int off = 1; off < 64; off <<= 1) {
        int u = __shfl_up(v, off);
        if (lane >= off) v += u;
    }
    if (lane == 63) wsum[wid] = v;
    __syncthreads();
    if (wid == 0) {
        int s = (lane < 16) ? wsum[lane] : 0;
#pragma unroll
        for (int off = 1; off < 16; off <<= 1) {
            int u = __shfl_up(s, off);
            if (lane >= off) s += u;
        }
        if (lane < 16) wsum[lane] = s;
    }
    __syncthreads();
    int wpre = wid ? wsum[wid - 1] : 0;
    if (idx < N_) rowptr[idx] = wpre + v - orig;
    if (tid == 0) tsum[blockIdx.x] = wsum[15];
}

// 2b) pass B: every block redundantly scans the 49 tile totals, adds its offset
__global__ __launch_bounds__(1024) void scan_b_kernel(const int* __restrict__ tsum,
                                                      int* __restrict__ rowptr) {
    __shared__ int soff[SCAN_TILES];
    __shared__ int stot;
    int tid = threadIdx.x, lane = tid & 63, wid = tid >> 6;
    if (wid == 0) {
        int own = (lane < SCAN_TILES) ? tsum[lane] : 0;
        int s = own;
#pragma unroll
        for (int off = 1; off < 64; off <<= 1) {
            int u = __shfl_up(s, off);
            if (lane >= off) s += u;
        }
        if (lane < SCAN_TILES) soff[lane] = s - own;  // exclusive
        if (lane == SCAN_TILES - 1) stot = s;
    }
    __syncthreads();
    int off = soff[blockIdx.x];
    int idx = blockIdx.x * 1024 + tid;
    if (idx < N_) rowptr[idx] += off;
    if (blockIdx.x == SCAN_TILES - 1 && tid == 0) rowptr[N_] = stot;
}

// 3) reorder edges into CSR-by-dst, dinv fused. Afterwards rowptr[d]==end(d),
//    start(d)==(d?rowptr[d-1]:0). Packs {src,nw}.
__global__ void reorder_kernel(const int* __restrict__ src, const int* __restrict__ dst,
                               const float* __restrict__ w, const float* __restrict__ degw,
                               int* __restrict__ rowptr, int2* __restrict__ es, int E) {
    int e = blockIdx.x * blockDim.x + threadIdx.x;
    if (e < E) {
        int s = src[e], d = dst[e];
        float ds = degw[s], dd = degw[d];
        float is = ds > 0.f ? rsqrtf(fmaxf(ds, 1e-12f)) : 0.f;
        float id = dd > 0.f ? rsqrtf(fmaxf(dd, 1e-12f)) : 0.f;
        float nwv = -w[e] * is * id;
        int pos = atomicAdd(&rowptr[d], 1);
        es[pos] = make_int2(s, __float_as_int(nwv));
    }
}

// 4) FUSED gather + node. Block = 4 nodes. Phase 1: each wave gathers one
//    node's tx1 rows (all 8 t) into a padded LDS tile. Phase 2: waves switch
//    to MFMA roles (wave = M-tile x {az,ah}); A-frags from xb/LDS, B-frags
//    straight from L2-hot swz. Phase 3: az crosses to the ah-wave via LDS,
//    epilogue + Wlin reduce + scattered out writes.
__global__ __launch_bounds__(256) void gather_node_kernel(
        const int* __restrict__ rowptr, const int2* __restrict__ es,
        const unsigned short* __restrict__ xb, const short* __restrict__ swz,
        const float* __restrict__ bxz, const float* __restrict__ bhz,
        const float* __restrict__ bxh, const float* __restrict__ bhh,
        const float* __restrict__ Wlin, const float* __restrict__ blin,
        float* __restrict__ out) {
    __shared__ unsigned short ltx[32 * 72];  // 32 rows x 64 ch bf16, +8 pad
    __shared__ float laz[2][16][64];         // az exchange, 8 KB

    int lane = threadIdx.x & 63;
    int wid = threadIdx.x >> 6;
    int base = blockIdx.x * 4;

    // ---- phase 1: gather node d = base + wid (lane = t*8 + oct) ----
    {
        int d = base + wid;
        int t = lane >> 3;
        int oct = lane & 7;
        int start = d ? rowptr[d - 1] : 0;
        int end = rowptr[d];
        float acc[8] = {0.f, 0.f, 0.f, 0.f, 0.f, 0.f, 0.f, 0.f};
        const unsigned short* xbase = xb + (long long)t * N_ * C_ + oct * 8;
        for (int b0 = start; b0 < end; b0 += 64) {
            int m = end - b0;
            if (m > 64) m = 64;
            int2 pk = (lane < m) ? es[b0 + lane] : make_int2(0, 0);
            int k = 0;
            for (; k + 1 < m; k += 2) {
                int s0 = __shfl(pk.x, k);
                float w0 = __int_as_float(__shfl(pk.y, k));
                int s1 = __shfl(pk.x, k + 1);
                float w1 = __int_as_float(__shfl(pk.y, k + 1));
                uint4 v0 = *(const uint4*)(xbase + (long long)s0 * C_);
                uint4 v1 = *(const uint4*)(xbase + (long long)s1 * C_);
                acc[0] += w0 * bf2f_lo(v0.x); acc[1] += w0 * bf2f_hi(v0.x);
                acc[2] += w0 * bf2f_lo(v0.y); acc[3] += w0 * bf2f_hi(v0.y);
                acc[4] += w0 * bf2f_lo(v0.z); acc[5] += w0 * bf2f_hi(v0.z);
                acc[6] += w0 * bf2f_lo(v0.w); acc[7] += w0 * bf2f_hi(v0.w);
                acc[0] += w1 * bf2f_lo(v1.x); acc[1] += w1 * bf2f_hi(v1.x);
                acc[2] += w1 * bf2f_lo(v1.y); acc[3] += w1 * bf2f_hi(v1.y);
                acc[4] += w1 * bf2f_lo(v1.z); acc[5] += w1 * bf2f_hi(v1.z);
                acc[6] += w1 * bf2f_lo(v1.w); acc[7] += w1 * bf2f_hi(v1.w);
            }
            if (k < m) {
                int s0 = __shfl(pk.x, k);
                float w0 = __int_as_float(__shfl(pk.y, k));
                uint4 v0 = *(const uint4*)(xbase + (long long)s0 * C_);
                acc[0] += w0 * bf2f_lo(v0.x); acc[1] += w0 * bf2f_hi(v0.x);
                acc[2] += w0 * bf2f_lo(v0.y); acc[3] += w0 * bf2f_hi(v0.y);
                acc[4] += w0 * bf2f_lo(v0.z); acc[5] += w0 * bf2f_hi(v0.z);
                acc[6] += w0 * bf2f_lo(v0.w); acc[7] += w0 * bf2f_hi(v0.w);
            }
        }
        uint4 o;
        o.x = (unsigned int)(unsigned short)f2bf(acc[0]) |
              ((unsigned int)(unsigned short)f2bf(acc[1]) << 16);
        o.y = (unsigned int)(unsigned short)f2bf(acc[2]) |
              ((unsigned int)(unsigned short)f2bf(acc[3]) << 16);
        o.z = (unsigned int)(unsigned short)f2bf(acc[4]) |
              ((unsigned int)(unsigned short)f2bf(acc[5]) << 16);
        o.w = (unsigned int)(unsigned short)f2bf(acc[6]) |
              ((unsigned int)(unsigned short)f2bf(acc[7]) << 16);
        int r = wid * 8 + t;  // block-row: r>>3 = node, r&7 = t
        *(uint4*)(ltx + r * 72 + oct * 8) = o;
    }
    __syncthreads();

    // ---- phase 2: MFMA. wave -> (M-tile mt, gate g: 0=az, 1=ah) ----
    int mt = wid >> 1;
    int g = wid & 1;
    int c16 = lane & 15;
    int kq = lane >> 4;
    int r_blk = mt * 16 + c16;
    int tt = r_blk & 7;
    int dd = base + (r_blk >> 3);

    const unsigned short* xr = xb + ((long long)tt * N_ + dd) * C_ + kq * 8;
    bf16x8 ax0 = *(const bf16x8*)(xr);
    bf16x8 ax1 = *(const bf16x8*)(xr + 32);
    bf16x8 at0 = *(const bf16x8*)(ltx + r_blk * 72 + kq * 8);
    bf16x8 at1 = *(const bf16x8*)(ltx + r_blk * 72 + 32 + kq * 8);

    const float* bA = g ? bxh : bxz;
    const float* bB = g ? bhh : bhz;
    const short* wA = swz + (2 * g) * 4096 + lane * 8;      // x-weight frags
    const short* wB = swz + (2 * g + 1) * 4096 + lane * 8;  // tx1-weight frags

    f32x4 a4[4];
#pragma unroll
    for (int c = 0; c < 4; ++c) {
        int col = c * 16 + c16;
        float bv = bA[col] + bB[col];
        a4[c] = (f32x4){bv, bv, bv, bv};
    }
#pragma unroll
    for (int c = 0; c < 4; ++c) {
        bf16x8 bA0 = *(const bf16x8*)(wA + (c * 2 + 0) * 512);
        bf16x8 bA1 = *(const bf16x8*)(wA + (c * 2 + 1) * 512);
        bf16x8 bB0 = *(const bf16x8*)(wB + (c * 2 + 0) * 512);
        bf16x8 bB1 = *(const bf16x8*)(wB + (c * 2 + 1) * 512);
        a4[c] = __builtin_amdgcn_mfma_f32_16x16x32_bf16(ax0, bA0, a4[c], 0, 0, 0);
        a4[c] = __builtin_amdgcn_mfma_f32_16x16x32_bf16(ax1, bA1, a4[c], 0, 0, 0);
        a4[c] = __builtin_amdgcn_mfma_f32_16x16x32_bf16(at0, bB0, a4[c], 0, 0, 0);
        a4[c] = __builtin_amdgcn_mfma_f32_16x16x32_bf16(at1, bB1, a4[c], 0, 0, 0);
    }

    // ---- phase 3: az -> LDS; ah-wave computes epilogue ----
    if (g == 0) {
#pragma unroll
        for (int c = 0; c < 4; ++c)
#pragma unroll
            for (int r = 0; r < 4; ++r)
                laz[mt][kq * 4 + r][c * 16 + c16] = a4[c][r];
    }
    __syncthreads();
    if (g == 1) {
        float part[4] = {0.f, 0.f, 0.f, 0.f};
#pragma unroll
        for (int c = 0; c < 4; ++c) {
            int col = c * 16 + c16;
            float wl = Wlin[col];
#pragma unroll
            for (int r = 0; r < 4; ++r) {
                float a = laz[mt][kq * 4 + r][col];
                float b = a4[c][r];
                float z = 1.f / (1.f + __expf(-a));
                float aa = fabsf(b);
                float e = __expf(-2.f * aa);
                float ht = copysignf((1.f - e) / (1.f + e), b);
                float h = fmaxf((1.f - z) * ht, 0.f);
                part[r] += h * wl;
            }
        }
#pragma unroll
        for (int m = 1; m <= 8; m <<= 1) {
#pragma unroll
            for (int r = 0; r < 4; ++r) part[r] += __shfl_xor(part[r], m);
        }
        if (c16 == 0) {
            float bl = blin[0];
#pragma unroll
            for (int r = 0; r < 4; ++r) {
                int rb = mt * 16 + kq * 4 + r;
                out[(long long)(rb & 7) * N_ + base + (rb >> 3)] = part[r] + bl;
            }
        }
    }
}

extern "C" void kernel_launch(void* const* d_in, const int* in_sizes, int n_in,
                              void* d_out, int out_size, void* d_ws, size_t ws_size,
                              hipStream_t stream) {
    const float* x    = (const float*)d_in[0];
    const int*   ei   = (const int*)d_in[1];
    const float* w    = (const float*)d_in[2];
    const float* Wxz0 = (const float*)d_in[3];
    const float* Wxz1 = (const float*)d_in[4];
    const float* bxz  = (const float*)d_in[5];
    const float* bhz  = (const float*)d_in[8];
    const float* Wxh0 = (const float*)d_in[15];
    const float* Wxh1 = (const float*)d_in[16];
    const float* bxh  = (const float*)d_in[17];
    const float* bhh  = (const float*)d_in[20];
    const float* Wlin = (const float*)d_in[21];
    const float* blin = (const float*)d_in[22];
    float* out = (float*)d_out;

    const int* src = ei;
    const int* dst = ei + E_;

    // workspace layout (512-aligned blocks):
    char* ws = (char*)d_ws;
    size_t off = 0;
    auto alloc = [&](size_t bytes) {
        char* p = ws + off;
        off = (off + bytes + 511) & ~(size_t)511;
        return p;
    };
    short* swz             = (short*)alloc(4 * 4096 * sizeof(short));           // 32 KB
    float* degw            = (float*)alloc((size_t)N_ * 4);
    int*   cnt             = (int*)alloc((size_t)N_ * 4);
    int*   rowptr          = (int*)alloc(((size_t)N_ + 1) * 4);
    int*   tsum            = (int*)alloc((size_t)SCAN_TILES * 4);
    int2*  es              = (int2*)alloc((size_t)E_ * 8);                      // 6.4 MB
    unsigned short* xb     = (unsigned short*)alloc((size_t)T_ * N_ * C_ * 2);  // 51.2 MB

    hipMemsetAsync(degw, 0, (size_t)N_ * 4, stream);
    hipMemsetAsync(cnt, 0, (size_t)N_ * 4, stream);

    // hist (3125) + xcvt (12500) + wprep (64) = 15689 blocks
    fused_prep_kernel<<<15689, 256, 0, stream>>>(src, dst, w, degw, cnt,
                                                 x, xb, Wxz0, Wxz1, Wxh0, Wxh1, swz);
    scan_a_kernel<<<SCAN_TILES, 1024, 0, stream>>>(cnt, rowptr, tsum);
    scan_b_kernel<<<SCAN_TILES, 1024, 0, stream>>>(tsum, rowptr);
    reorder_kernel<<<(E_ + 255) / 256, 256, 0, stream>>>(src, dst, w, degw, rowptr, es, E_);

    // 12500 blocks x 4 nodes = 50000
    gather_node_kernel<<<N_ / 4, 256, 0, stream>>>(
        rowptr, es, xb, swz, bxz, bhz, bxh, bhh, Wlin, blin, out);
}